// Round 4
// baseline (1604.626 us; speedup 1.0000x reference)
//
#include <hip/hip_runtime.h>
#include <cstdint>
#include <cmath>

// ---------------------------------------------------------------------------
// Informer forward. Round 19: deeper counted pipeline + LDS bank-deswizzle.
//  - gemm12864_k: 4-buffer depth-3 counted pipeline (vmcnt 6/3/0). R18's
//    depth-1 left ~600cyc/step exposed (HBM ~900cyc vs ~300cyc flight).
//  - gemm128_k: 3-buffer depth-2 (vmcnt 4/0), 48KB LDS keeps 3 blocks/CU.
//  - Both: XOR swizzle seg^((row>>1)&3) applied to global SOURCE addr and
//    LDS READ addr (linear DMA dest, rule-21 compliant) — kills the 8-way
//    ds_read_b128 bank conflict of the linear layout (3.1M/dispatch in R18).
//  - Same iteration skeleton as R18 (proven): stage -> compute -> counted
//    wait -> s_barrier -> sched_barrier.
// jax.random via threefry2x32 (H2, verified R1).
// ---------------------------------------------------------------------------

#define HD __host__ __device__

typedef short short8 __attribute__((ext_vector_type(8)));
typedef float float4v __attribute__((ext_vector_type(4)));

typedef __attribute__((address_space(1))) const void gvoid;
typedef __attribute__((address_space(3))) void lvoid;

__device__ __forceinline__ void gl_lds16(const void* g, void* l) {
    // async global->LDS DMA, 16B/lane; LDS dest = wave-uniform base + lane*16
    __builtin_amdgcn_global_load_lds((gvoid*)g, (lvoid*)l, 16, 0, 0);
}

__device__ inline short f2bf(float f) {  // RNE
    unsigned u = __float_as_uint(f);
    unsigned r = u + 0x7FFFu + ((u >> 16) & 1u);
    return (short)(r >> 16);
}

HD inline unsigned rotl32(unsigned x, int r) { return (x << r) | (x >> (32 - r)); }
HD inline void tfround(unsigned& x0, unsigned& x1, int r) {
    x0 += x1; x1 = rotl32(x1, r); x1 ^= x0;
}
HD inline void threefry2x32(unsigned k0, unsigned k1, unsigned c0, unsigned c1,
                            unsigned& o0, unsigned& o1) {
    unsigned ks2 = k0 ^ k1 ^ 0x1BD11BDAu;
    unsigned x0 = c0 + k0, x1 = c1 + k1;
    tfround(x0, x1, 13); tfround(x0, x1, 15); tfround(x0, x1, 26); tfround(x0, x1, 6);
    x0 += k1; x1 += ks2 + 1u;
    tfround(x0, x1, 17); tfround(x0, x1, 29); tfround(x0, x1, 16); tfround(x0, x1, 24);
    x0 += ks2; x1 += k0 + 2u;
    tfround(x0, x1, 13); tfround(x0, x1, 15); tfround(x0, x1, 26); tfround(x0, x1, 6);
    x0 += k0; x1 += k1 + 3u;
    tfround(x0, x1, 17); tfround(x0, x1, 29); tfround(x0, x1, 16); tfround(x0, x1, 24);
    x0 += k1; x1 += ks2 + 4u;
    tfround(x0, x1, 13); tfround(x0, x1, 15); tfround(x0, x1, 26); tfround(x0, x1, 6);
    x0 += ks2; x1 += k0 + 5u;
    o0 = x0; o1 = x1;
}

// ---------------------------------------------------------------------------
// Kernels
// ---------------------------------------------------------------------------

// out = in + PE; outb = bf16(out)
__global__ void pe_add_k(const float* __restrict__ in, float* __restrict__ out,
                         short* __restrict__ outb, int total) {
    int t = blockIdx.x * 256 + threadIdx.x;
    if (t >= total) return;
    int d = t % 512;
    int l = (t / 512) % 512;
    float i2 = (float)(d & ~1);
    float div = expf(i2 * (-0.017988946039016f));  // -ln(10000)/512
    float ang = (float)l * div;
    float v = (d & 1) ? cosf(ang) : sinf(ang);
    float r = in[t] + v;
    out[t] = r;
    outb[t] = f2bf(r);
}

// fp32 [K][N] -> bf16 [N][K] via 32x32 LDS tile
__global__ __launch_bounds__(256) void transpose_bf16_k(const float* __restrict__ in,
                                                        short* __restrict__ out, int K, int N) {
    __shared__ float tile[32][33];
    int k0 = blockIdx.y * 32, n0 = blockIdx.x * 32;
    int c = threadIdx.x & 31, r0 = threadIdx.x >> 5;
    for (int rr = r0; rr < 32; rr += 8)
        tile[rr][c] = in[(size_t)(k0 + rr) * N + n0 + c];
    __syncthreads();
    for (int rr = r0; rr < 32; rr += 8)
        out[(size_t)(n0 + rr) * K + k0 + c] = f2bf(tile[c][rr]);
}

// dist_w (O,I,H) -> bf16 W2T[o][h*512+i]
__global__ void w2t_k(const float* __restrict__ dw, short* __restrict__ out, int total) {
    int t = blockIdx.x * 256 + threadIdx.x;
    if (t >= total) return;
    int kk = t % 1536;
    int o = t / 1536;
    int h = kk / 512, i = kk % 512;
    out[t] = f2bf(dw[(size_t)o * 1536 + i * 3 + h]);
}

// concat biases bq|bk|bv -> bqkv[1536]
__global__ void bcat_k(const float* __restrict__ b0, const float* __restrict__ b1,
                       const float* __restrict__ b2, float* __restrict__ out) {
    int t = blockIdx.x * 256 + threadIdx.x;
    if (t >= 1536) return;
    out[t] = (t < 512) ? b0[t] : (t < 1024 ? b1[t - 512] : b2[t - 1024]);
}

__device__ inline void swizzle_bid(int bid, int nbx, int nby, int& bm, int& bn) {
    if ((nby & 7) == 0) {
        int stripe = nby >> 3;
        int x = bid & 7, w = bid >> 3;
        bn = w % nbx;
        bm = x * stripe + w / nbx;
    } else {
        bn = bid % nbx;
        bm = bid / nbx;
    }
}

// bf16 MFMA GEMM, 128x128 tile, BK=32; A bf16 [M][K], Bt bf16 [N][K].
// 3-buffer depth-2 counted pipeline + bank-deswizzled staging/reads.
__global__ __launch_bounds__(256) void gemm128_k(
    const short* __restrict__ A, const short* __restrict__ Bt,
    const float* __restrict__ bias, const float* __restrict__ res,
    float* __restrict__ C32, short* __restrict__ C16,
    int M, int N, int K, int relu, int ldC) {
    __shared__ short As[3][128 * 32];
    __shared__ short Bs[3][128 * 32];
    int tid = threadIdx.x;
    int wave = tid >> 6, lane = tid & 63;
    int wy = wave >> 1, wx = wave & 1;
    int rl = lane & 15, quad = lane >> 4;
    int bm, bn;
    swizzle_bid(blockIdx.x, N >> 7, M >> 7, bm, bn);
    bm <<= 7; bn <<= 7;

    // staging: wave w covers rows w*32..w*32+31 (2 DMA chunks of 16 rows);
    // lane -> row = lane/4, k-seg = lane&3. Global source k-seg is XOR-permuted
    // by ((row>>1)&3) (invariant under +16 rows); LDS dest stays linear.
    int srow = (wave << 5) + (lane >> 2);
    int skol = (((lane & 3) ^ ((srow >> 1) & 3)) << 3);
    const short* ga0 = A + (size_t)(bm + srow) * K + skol;
    const short* ga1 = ga0 + (size_t)16 * K;
    const short* gb0 = Bt + (size_t)(bn + srow) * K + skol;
    const short* gb1 = gb0 + (size_t)16 * K;
    int lao = wave << 10;
    int ksw = (quad ^ ((rl >> 1) & 3)) << 3;  // read-side swizzle (same involution)

    float4v acc[4][4];
    #pragma unroll
    for (int i = 0; i < 4; i++)
        #pragma unroll
        for (int j = 0; j < 4; j++) acc[i][j] = (float4v){0.f, 0.f, 0.f, 0.f};

    int nsteps = K >> 5;
    auto stage = [&](int t, int bf) {
        int k0 = t << 5;
        gl_lds16(ga0 + k0, &As[bf][lao]);
        gl_lds16(ga1 + k0, &As[bf][lao + 512]);
        gl_lds16(gb0 + k0, &Bs[bf][lao]);
        gl_lds16(gb1 + k0, &Bs[bf][lao + 512]);
    };
    // prologue: stages 0,1 issued; wait for stage 0 only (4 loads in flight)
    stage(0, 0);
    stage(1, 1);
    asm volatile("s_waitcnt vmcnt(4)" ::: "memory");
    __builtin_amdgcn_s_barrier();
    __builtin_amdgcn_sched_barrier(0);
    int cur = 0;
    for (int t = 0; t < nsteps; ++t) {
        if (t + 2 < nsteps) {
            int sb = cur + 2; if (sb >= 3) sb -= 3;
            stage(t + 2, sb);
        }
        short8 a[4], b[4];
        #pragma unroll
        for (int i = 0; i < 4; i++)
            a[i] = *(const short8*)&As[cur][(wy * 64 + i * 16 + rl) * 32 + ksw];
        #pragma unroll
        for (int j = 0; j < 4; j++)
            b[j] = *(const short8*)&Bs[cur][(wx * 64 + j * 16 + rl) * 32 + ksw];
        #pragma unroll
        for (int i = 0; i < 4; i++)
            #pragma unroll
            for (int j = 0; j < 4; j++)
                acc[i][j] = __builtin_amdgcn_mfma_f32_16x16x32_bf16(a[i], b[j], acc[i][j], 0, 0, 0);
        // stage(t+1) must be complete; stage(t+2) stays in flight
        if (t + 2 < nsteps) {
            asm volatile("s_waitcnt vmcnt(4)" ::: "memory");
        } else {
            asm volatile("s_waitcnt vmcnt(0)" ::: "memory");
        }
        __builtin_amdgcn_s_barrier();
        __builtin_amdgcn_sched_barrier(0);
        cur = (cur == 2) ? 0 : cur + 1;
    }
    #pragma unroll
    for (int i = 0; i < 4; i++) {
        #pragma unroll
        for (int r = 0; r < 4; r++) {
            int gm = bm + wy * 64 + i * 16 + quad * 4 + r;
            #pragma unroll
            for (int j = 0; j < 4; j++) {
                int gn = bn + wx * 64 + j * 16 + rl;
                float v = acc[i][j][r];
                if (bias) v += bias[gn];
                if (relu) v = fmaxf(v, 0.f);
                if (res) v += res[(size_t)gm * ldC + gn];
                if (C32) C32[(size_t)gm * ldC + gn] = v;
                if (C16) C16[(size_t)gm * ldC + gn] = f2bf(v);
            }
        }
    }
}

// 128x64 tile, BK=32, 4 waves 2x2, per-wave 64x32 output.
// 4-buffer depth-3 counted pipeline + bank-deswizzled staging/reads.
__global__ __launch_bounds__(256) void gemm12864_k(
    const short* __restrict__ A, const short* __restrict__ Bt,
    const float* __restrict__ bias, const float* __restrict__ res,
    float* __restrict__ C32, short* __restrict__ C16,
    int M, int N, int K, int relu, int ldC) {
    __shared__ short As[4][128 * 32];
    __shared__ short Bs[4][64 * 32];
    int tid = threadIdx.x;
    int wave = tid >> 6, lane = tid & 63;
    int wy = wave >> 1, wx = wave & 1;
    int rl = lane & 15, quad = lane >> 4;
    int bm, bn;
    swizzle_bid(blockIdx.x, N >> 6, M >> 7, bm, bn);
    bm <<= 7; bn <<= 6;

    int arow = (wave << 5) + (lane >> 2);   // A: wave covers 32 rows (2 chunks)
    int brow = (wave << 4) + (lane >> 2);   // B: wave covers 16 rows (1 chunk)
    int ska = (((lane & 3) ^ ((arow >> 1) & 3)) << 3);
    int skb = (((lane & 3) ^ ((brow >> 1) & 3)) << 3);
    const short* ga0 = A + (size_t)(bm + arow) * K + ska;
    const short* ga1 = ga0 + (size_t)16 * K;
    const short* gb0 = Bt + (size_t)(bn + brow) * K + skb;
    int lao = wave << 10;
    int lbo = wave << 9;
    int ksw = (quad ^ ((rl >> 1) & 3)) << 3;

    float4v acc[4][2];
    #pragma unroll
    for (int i = 0; i < 4; i++)
        #pragma unroll
        for (int j = 0; j < 2; j++) acc[i][j] = (float4v){0.f, 0.f, 0.f, 0.f};

    int nsteps = K >> 5;
    auto stage = [&](int t, int bf) {
        int k0 = t << 5;
        gl_lds16(ga0 + k0, &As[bf][lao]);
        gl_lds16(ga1 + k0, &As[bf][lao + 512]);
        gl_lds16(gb0 + k0, &Bs[bf][lbo]);
    };
    // prologue: stages 0,1,2 issued; wait for stage 0 (6 loads in flight)
    stage(0, 0);
    stage(1, 1);
    stage(2, 2);
    asm volatile("s_waitcnt vmcnt(6)" ::: "memory");
    __builtin_amdgcn_s_barrier();
    __builtin_amdgcn_sched_barrier(0);
    for (int t = 0; t < nsteps; ++t) {
        int cur = t & 3;
        if (t + 3 < nsteps) stage(t + 3, (t + 3) & 3);
        short8 a[4], b[2];
        #pragma unroll
        for (int i = 0; i < 4; i++)
            a[i] = *(const short8*)&As[cur][(wy * 64 + i * 16 + rl) * 32 + ksw];
        #pragma unroll
        for (int j = 0; j < 2; j++)
            b[j] = *(const short8*)&Bs[cur][(wx * 32 + j * 16 + rl) * 32 + ksw];
        #pragma unroll
        for (int i = 0; i < 4; i++)
            #pragma unroll
            for (int j = 0; j < 2; j++)
                acc[i][j] = __builtin_amdgcn_mfma_f32_16x16x32_bf16(a[i], b[j], acc[i][j], 0, 0, 0);
        // stage(t+1) must be complete; stages t+2,t+3 stay in flight
        if (t + 3 < nsteps) {
            asm volatile("s_waitcnt vmcnt(6)" ::: "memory");
        } else if (t + 2 < nsteps) {
            asm volatile("s_waitcnt vmcnt(3)" ::: "memory");
        } else {
            asm volatile("s_waitcnt vmcnt(0)" ::: "memory");
        }
        __builtin_amdgcn_s_barrier();
        __builtin_amdgcn_sched_barrier(0);
    }
    #pragma unroll
    for (int i = 0; i < 4; i++) {
        #pragma unroll
        for (int r = 0; r < 4; r++) {
            int gm = bm + wy * 64 + i * 16 + quad * 4 + r;
            #pragma unroll
            for (int j = 0; j < 2; j++) {
                int gn = bn + wx * 32 + j * 16 + rl;
                float v = acc[i][j][r];
                if (bias) v += bias[gn];
                if (relu) v = fmaxf(v, 0.f);
                if (res) v += res[(size_t)gm * ldC + gn];
                if (C32) C32[(size_t)gm * ldC + gn] = v;
                if (C16) C16[(size_t)gm * ldC + gn] = f2bf(v);
            }
        }
    }
}

// 64x64-tile variant, BK=32. 4 waves, each 16x64. (small-M fallback)
__global__ __launch_bounds__(256) void gemm64_k(
    const short* __restrict__ A, const short* __restrict__ Bt,
    const float* __restrict__ bias, const float* __restrict__ res,
    float* __restrict__ C32, short* __restrict__ C16,
    int M, int N, int K, int relu, int ldC) {
    __shared__ short As[64 * 40];
    __shared__ short Bs[64 * 40];
    int tid = threadIdx.x;
    int wave = tid >> 6, lane = tid & 63;
    int rl = lane & 15, quad = lane >> 4;
    int bm, bn;
    swizzle_bid(blockIdx.x, N >> 6, M >> 6, bm, bn);
    bm <<= 6; bn <<= 6;

    float4v acc[4];
    #pragma unroll
    for (int j = 0; j < 4; j++) acc[j] = (float4v){0.f, 0.f, 0.f, 0.f};

    int row = tid >> 2, seg = tid & 3;
    for (int k0 = 0; k0 < K; k0 += 32) {
        *(float4*)&As[row * 40 + seg * 8] =
            *(const float4*)(A + (size_t)(bm + row) * K + k0 + seg * 8);
        *(float4*)&Bs[row * 40 + seg * 8] =
            *(const float4*)(Bt + (size_t)(bn + row) * K + k0 + seg * 8);
        __syncthreads();
        short8 a = *(const short8*)&As[(wave * 16 + rl) * 40 + quad * 8];
        short8 b[4];
        #pragma unroll
        for (int j = 0; j < 4; j++)
            b[j] = *(const short8*)&Bs[(j * 16 + rl) * 40 + quad * 8];
        #pragma unroll
        for (int j = 0; j < 4; j++)
            acc[j] = __builtin_amdgcn_mfma_f32_16x16x32_bf16(a, b[j], acc[j], 0, 0, 0);
        __syncthreads();
    }
    #pragma unroll
    for (int r = 0; r < 4; r++) {
        int gm = bm + wave * 16 + quad * 4 + r;
        #pragma unroll
        for (int j = 0; j < 4; j++) {
            int gn = bn + j * 16 + rl;
            float v = acc[j][r];
            if (bias) v += bias[gn];
            if (relu) v = fmaxf(v, 0.f);
            if (res) v += res[(size_t)gm * ldC + gn];
            if (C32) C32[(size_t)gm * ldC + gn] = v;
            if (C16) C16[(size_t)gm * ldC + gn] = f2bf(v);
        }
    }
}

// idx[j] = threefry(rkey, (j, j+size)).second & mask   (H2, verified R1)
__global__ void ridx_k(unsigned k0, unsigned k1, int size, unsigned mask, int* __restrict__ idx) {
    int j = blockIdx.x * 256 + threadIdx.x;
    if (j >= size) return;
    unsigned o0, o1;
    threefry2x32(k0, k1, (unsigned)j, (unsigned)(j + size), o0, o1);
    idx[j] = (int)(o1 & mask);
}

// msamp, K-slab in LDS. One block per (b, h, l-half); grid 16*8*2 = 256.
extern __shared__ float kslab[];
__global__ __launch_bounds__(256) void msamp_lds_k(
    const float* __restrict__ Qp, const float* __restrict__ Kp,
    const int* __restrict__ idx, float* __restrict__ Mout,
    int LQ, int LK, int U, int ld) {
    int bid = blockIdx.x;
    int half = bid & 1;
    int bh = bid >> 1;
    int h = bh & 7, b = bh >> 3;
    const float* kbase = Kp + (size_t)b * LK * ld + h * 64;
    for (int t = threadIdx.x; t < LK * 16; t += 256) {
        int r = t >> 4, seg = t & 15;
        float4 v = *(const float4*)(kbase + (size_t)r * ld + seg * 4);
        float* dst = &kslab[r * 65 + seg * 4];
        dst[0] = v.x; dst[1] = v.y; dst[2] = v.z; dst[3] = v.w;
    }
    __syncthreads();
    int halfL = LQ >> 1;
    for (int li = threadIdx.x; li < halfL; li += 256) {
        int l = half * halfL + li;
        const float4* q = (const float4*)(Qp + (size_t)(b * LQ + l) * ld + h * 64);
        float qr[64];
        #pragma unroll
        for (int d4 = 0; d4 < 16; d4++) {
            float4 v = q[d4];
            qr[4 * d4] = v.x; qr[4 * d4 + 1] = v.y; qr[4 * d4 + 2] = v.z; qr[4 * d4 + 3] = v.w;
        }
        const int* ip = idx + l * U;
        float mx = -INFINITY, sm = 0.f;
        for (int s = 0; s < U; s++) {
            const float* kr = &kslab[ip[s] * 65];
            float acc = 0.f;
            #pragma unroll
            for (int d = 0; d < 64; d++) acc += qr[d] * kr[d];
            mx = fmaxf(mx, acc);
            sm += acc;
        }
        Mout[(size_t)bh * LQ + l] = mx - sm / (float)LK;
    }
}

// Fallback msamp if large dynamic-LDS attribute fails.
__global__ void msamp_k(const float* __restrict__ Qp, const float* __restrict__ Kp,
                        const int* __restrict__ idx, float* __restrict__ Mout,
                        int LQ, int LK, int U, int ld) {
    int t = blockIdx.x * 256 + threadIdx.x;
    int total = 16 * 8 * LQ * 4;
    if (t >= total) return;
    int p = t & 3;
    int rest = t >> 2;
    int l = rest % LQ;
    int h = (rest / LQ) & 7;
    int b = rest / (LQ * 8);
    const float4* q = (const float4*)(Qp + ((size_t)(b * LQ + l) * ld + h * 64));
    const float* kb = Kp + ((size_t)b * LK * ld + h * 64);
    float4 qr[16];
    #pragma unroll
    for (int d = 0; d < 16; d++) qr[d] = q[d];
    float mx = -INFINITY, sm = 0.f;
    for (int s = p; s < U; s += 4) {
        const float4* kr = (const float4*)(kb + (size_t)idx[l * U + s] * ld);
        float acc = 0.f;
        #pragma unroll
        for (int d = 0; d < 16; d++) {
            float4 kv = kr[d];
            acc += qr[d].x * kv.x + qr[d].y * kv.y + qr[d].z * kv.z + qr[d].w * kv.w;
        }
        mx = fmaxf(mx, acc);
        sm += acc;
    }
    mx = fmaxf(mx, __shfl_xor(mx, 1));
    mx = fmaxf(mx, __shfl_xor(mx, 2));
    sm += __shfl_xor(sm, 1);
    sm += __shfl_xor(sm, 2);
    if (p == 0)
        Mout[(size_t)((b * 8) + h) * LQ + l] = mx - sm / (float)LK;
}

// Parallel top-u per (b,h): iterative argmax in LDS, lowest-index tie-break.
__global__ __launch_bounds__(256) void topk_k(const float* __restrict__ M,
                                              int* __restrict__ top, int LQ, int u) {
    __shared__ float vals[512];
    __shared__ float rv[256];
    __shared__ int ri[256];
    int bh = blockIdx.x;
    int tid = threadIdx.x;
    const float* m = M + (size_t)bh * LQ;
    for (int l = tid; l < LQ; l += 256) vals[l] = m[l];
    __syncthreads();
    for (int j = 0; j < u; j++) {
        float best = -INFINITY;
        int bi = LQ;
        for (int l = tid; l < LQ; l += 256) {
            float v = vals[l];
            if (v > best) { best = v; bi = l; }
        }
        rv[tid] = best; ri[tid] = bi;
        __syncthreads();
        for (int s = 128; s > 0; s >>= 1) {
            if (tid < s) {
                float v2 = rv[tid + s]; int i2 = ri[tid + s];
                if (v2 > rv[tid] || (v2 == rv[tid] && i2 < ri[tid])) { rv[tid] = v2; ri[tid] = i2; }
            }
            __syncthreads();
        }
        int sel = ri[0];
        if (tid == 0) {
            top[bh * u + j] = sel;
            vals[sel] = -INFINITY;
        }
        __syncthreads();
    }
}

// vm[b,c] = mean over l of V[b,l,c]; parallel over l. grid (16 c-chunks, 16 b).
__global__ __launch_bounds__(256) void vmean_k(const float* __restrict__ Vp,
                                               float* __restrict__ vm, int LK, int ld) {
    __shared__ float red[8][33];
    int b = blockIdx.y;
    int c0 = blockIdx.x * 32;
    int ci = threadIdx.x & 31, g = threadIdx.x >> 5;
    const float* base = Vp + (size_t)b * LK * ld + c0 + ci;
    float s = 0.f;
    for (int l = g; l < LK; l += 8) s += base[(size_t)l * ld];
    red[g][ci] = s;
    __syncthreads();
    if (threadIdx.x < 32) {
        float t = 0.f;
        #pragma unroll
        for (int g2 = 0; g2 < 8; g2++) t += red[g2][threadIdx.x];
        vm[b * 512 + c0 + threadIdx.x] = t / (float)LK;
    }
}

// ctxb[b,l,c] = bf16(vm[b,c])
__global__ void ctx_fill_k(const float* __restrict__ vm, short* __restrict__ ctxb,
                           int LQ, int total) {
    int t = blockIdx.x * 256 + threadIdx.x;
    if (t >= total) return;
    int c = t % 512;
    int b = t / (512 * LQ);
    ctxb[t] = f2bf(vm[b * 512 + c]);
}

// Flash-style ProbSparse attention: one block per (b, h, u-half), 256 threads.
__global__ __launch_bounds__(256) void attn_flash_k(
    const float* __restrict__ Qp, const float* __restrict__ Kp, const float* __restrict__ Vp,
    const int* __restrict__ top, short* __restrict__ ctxb, int LQ, int LK, int u, int ld) {
    __shared__ float qs[18][64];
    __shared__ int ls[18];
    __shared__ float kv[64][65];
    __shared__ float sc[18][512];
    int bid = blockIdx.x;
    int chunk = bid & 1;  // 2 chunks per (b,h)
    int h = (bid >> 1) & 7;
    int b = bid >> 4;
    int CH = (u + 1) >> 1;
    int r0 = chunk * CH;
    int nr = min(CH, u - r0);
    int tid = threadIdx.x;
    int wave = tid >> 6, lane = tid & 63;

    if (tid < nr) ls[tid] = top[((b * 8) + h) * u + r0 + tid];
    __syncthreads();
    for (int t = tid; t < nr * 16; t += 256) {
        int r = t >> 4, seg = t & 15;
        float4 v = *(const float4*)(Qp + ((size_t)(b * LQ + ls[r])) * ld + h * 64 + seg * 4);
        float* dst = &qs[r][seg * 4];
        dst[0] = v.x; dst[1] = v.y; dst[2] = v.z; dst[3] = v.w;
    }

    int ntile = LK >> 6;
    const float* kbase = Kp + ((size_t)b * LK) * ld + h * 64;
    for (int T = 0; T < ntile; T++) {
        __syncthreads();
        #pragma unroll
        for (int it = 0; it < 4; it++) {
            int t = tid + it * 256;
            int kk = t >> 4, seg = t & 15;
            float4 v = *(const float4*)(kbase + (size_t)(T * 64 + kk) * ld + seg * 4);
            float* dst = &kv[kk][seg * 4];
            dst[0] = v.x; dst[1] = v.y; dst[2] = v.z; dst[3] = v.w;
        }
        __syncthreads();
        for (int p = tid; p < nr * 64; p += 256) {
            int r = p >> 6, kk = p & 63;
            float acc = 0.f;
            #pragma unroll
            for (int d = 0; d < 64; d++) acc += qs[r][d] * kv[kk][d];
            sc[r][T * 64 + kk] = acc * 0.125f;  // 1/sqrt(64)
        }
    }
    __syncthreads();
    for (int r = wave; r < nr; r += 4) {
        float mx = -INFINITY;
        for (int k = lane; k < LK; k += 64) mx = fmaxf(mx, sc[r][k]);
        #pragma unroll
        for (int o = 32; o > 0; o >>= 1) mx = fmaxf(mx, __shfl_xor(mx, o));
        float s = 0.f;
        for (int k = lane; k < LK; k += 64) {
            float e = expf(sc[r][k] - mx);
            sc[r][k] = e;
            s += e;
        }
        #pragma unroll
        for (int o = 32; o > 0; o >>= 1) s += __shfl_xor(s, o);
        float inv = 1.0f / s;
        for (int k = lane; k < LK; k += 64) sc[r][k] *= inv;
    }
    float acc[5];
    #pragma unroll
    for (int i = 0; i < 5; i++) acc[i] = 0.f;
    const float* vbase = Vp + ((size_t)b * LK) * ld + h * 64;
    for (int T = 0; T < ntile; T++) {
        __syncthreads();
        #pragma unroll
        for (int it = 0; it < 4; it++) {
            int t = tid + it * 256;
            int kk = t >> 4, seg = t & 15;
            float4 v = *(const float4*)(vbase + (size_t)(T * 64 + kk) * ld + seg * 4);
            float* dst = &kv[kk][seg * 4];
            dst[0] = v.x; dst[1] = v.y; dst[2] = v.z; dst[3] = v.w;
        }
        __syncthreads();
        int ri = 0;
        for (int r = wave; r < nr; r += 4, ri++) {
            float a = 0.f;
            #pragma unroll
            for (int kk = 0; kk < 64; kk++) a += sc[r][T * 64 + kk] * kv[kk][lane];
            acc[ri] += a;
        }
    }
    int ri = 0;
    for (int r = wave; r < nr; r += 4, ri++)
        ctxb[((size_t)(b * LQ + ls[r])) * 512 + h * 64 + lane] = f2bf(acc[ri]);
}

// per-row layer norm, D=512; optional bf16 mirror
__global__ __launch_bounds__(256) void ln_k(const float* __restrict__ in,
                                            float* __restrict__ out, short* __restrict__ outb) {
    __shared__ float red[256];
    int r = blockIdx.x;
    int tid = threadIdx.x;
    const float* x = in + (size_t)r * 512;
    float a = x[tid], b = x[tid + 256];
    red[tid] = a + b;
    __syncthreads();
    for (int s = 128; s > 0; s >>= 1) {
        if (tid < s) red[tid] += red[tid + s];
        __syncthreads();
    }
    float mu = red[0] / 512.f;
    __syncthreads();
    float d1 = a - mu, d2 = b - mu;
    red[tid] = d1 * d1 + d2 * d2;
    __syncthreads();
    for (int s = 128; s > 0; s >>= 1) {
        if (tid < s) red[tid] += red[tid + s];
        __syncthreads();
    }
    float inv = 1.0f / sqrtf(red[0] / 512.f + 1e-5f);
    float v1 = d1 * inv, v2 = d2 * inv;
    out[(size_t)r * 512 + tid] = v1;
    out[(size_t)r * 512 + tid + 256] = v2;
    if (outb) {
        outb[(size_t)r * 512 + tid] = f2bf(v1);
        outb[(size_t)r * 512 + tid + 256] = f2bf(v2);
    }
}

// circular-pad im2col -> bf16
__global__ void xcat_k(const float* __restrict__ x, short* __restrict__ xc, int L, int total) {
    int t = blockIdx.x * 256 + threadIdx.x;
    if (t >= total) return;
    int i = t % 512;
    int h = (t / 512) % 3;
    int bt = t / 1536;
    int tt = bt % L;
    int b = bt / L;
    int src = (tt + h - 1 + L) % L;
    xc[t] = f2bf(x[(size_t)(b * L + src) * 512 + i]);
}

// bn stage 1: per-chunk per-channel sum/sumsq, coalesced row reads. grid=128.
__global__ __launch_bounds__(256) void bnpart_k(const float* __restrict__ y,
                                                float* __restrict__ ps, float* __restrict__ pq,
                                                int rows) {
    int chunk = blockIdx.x;
    int rpc = rows >> 7;
    int r0 = chunk * rpc;
    int tid = threadIdx.x;
    float s0 = 0.f, s1 = 0.f, q0 = 0.f, q1 = 0.f;
    for (int r = r0; r < r0 + rpc; r++) {
        float a = y[(size_t)r * 512 + tid];
        float b = y[(size_t)r * 512 + tid + 256];
        s0 += a; q0 += a * a;
        s1 += b; q1 += b * b;
    }
    ps[chunk * 512 + tid] = s0;
    ps[chunk * 512 + tid + 256] = s1;
    pq[chunk * 512 + tid] = q0;
    pq[chunk * 512 + tid + 256] = q1;
}

// bn stage 2: mu = s/n; var = q/n - mu^2.
__global__ void bnfin_k(const float* __restrict__ ps, const float* __restrict__ pq,
                        float* __restrict__ mu, float* __restrict__ var, int rows) {
    int o = blockIdx.x * 256 + threadIdx.x;
    if (o >= 512) return;
    float s = 0.f, q = 0.f;
    for (int c = 0; c < 128; c++) {
        s += ps[c * 512 + o];
        q += pq[c * 512 + o];
    }
    float m = s / (float)rows;
    mu[o] = m;
    var[o] = q / (float)rows - m * m;
}

// normalize -> max-pool(3,2,pad1) -> elu; writes fp32 + bf16 mirror
__global__ void elu_pool_k(const float* __restrict__ y, const float* __restrict__ mu,
                           const float* __restrict__ var, float* __restrict__ out,
                           short* __restrict__ outb, int L, int total) {
    int t = blockIdx.x * 256 + threadIdx.x;
    if (t >= total) return;
    int o = t % 512;
    int tp = (t / 512) % (L / 2);
    int b = t / (512 * (L / 2));
    float mm = mu[o];
    float inv = 1.0f / sqrtf(var[o] + 1e-5f);
    float m = -INFINITY;
    #pragma unroll
    for (int dt = 0; dt < 3; dt++) {
        int tt = 2 * tp - 1 + dt;
        if (tt < 0 || tt >= L) continue;
        float v = (y[(size_t)(b * L + tt) * 512 + o] - mm) * inv;
        m = fmaxf(m, v);
    }
    float r = m > 0.f ? m : expm1f(m);
    out[t] = r;
    outb[t] = f2bf(r);
}

// out[r] = dot(x[r,:512], w) + b
__global__ void final_k(const float* __restrict__ x, const float* __restrict__ w,
                        const float* __restrict__ bb, float* __restrict__ out, int rows) {
    int gid = blockIdx.x * 256 + threadIdx.x;
    int wid = gid >> 6;
    int lane = gid & 63;
    if (wid >= rows) return;
    const float* xr = x + (size_t)wid * 512;
    float acc = 0.f;
    for (int k = lane; k < 512; k += 64) acc += xr[k] * w[k];
    for (int off = 32; off > 0; off >>= 1) acc += __shfl_down(acc, off);
    if (lane == 0) out[wid] = acc + bb[0];
}

// ---------------------------------------------------------------------------
// Host driver
// ---------------------------------------------------------------------------

static inline int iceil_log(int L) { return (int)ceil(log((double)L)); }
static inline int imin(int a, int b) { return a < b ? a : b; }

extern "C" void kernel_launch(void* const* d_in, const int* in_sizes, int n_in,
                              void* d_out, int out_size, void* d_ws, size_t ws_size,
                              hipStream_t stream) {
    const float* IN  = (const float*)d_in[0];
    const float* Wq  = (const float*)d_in[1];
    const float* bq  = (const float*)d_in[2];
    const float* Wk  = (const float*)d_in[3];
    const float* bk  = (const float*)d_in[4];
    const float* Wv  = (const float*)d_in[5];
    const float* bv  = (const float*)d_in[6];
    const float* Wo  = (const float*)d_in[7];
    const float* bo  = (const float*)d_in[8];
    const float* ew1 = (const float*)d_in[9];
    const float* eb1 = (const float*)d_in[10];
    const float* ew2 = (const float*)d_in[11];
    const float* eb2 = (const float*)d_in[12];
    const float* dw1 = (const float*)d_in[13];
    const float* db1 = (const float*)d_in[14];
    const float* dw2 = (const float*)d_in[15];
    const float* db2 = (const float*)d_in[16];
    const float* DW  = (const float*)d_in[17];
    const float* db  = (const float*)d_in[18];
    const float* ow  = (const float*)d_in[19];
    const float* ob  = (const float*)d_in[20];
    float* OUT = (float*)d_out;

    float* ws = (float*)d_ws;
    size_t off = 0;
    auto alloc = [&](size_t n) { float* p = ws + off; off += n; return p; };
    float* PE   = alloc(4194304);
    short* PEb  = (short*)alloc(2097152);
    float* QKV  = alloc(12582912);
    float* CTX  = alloc(4194304);
    short* CTXb = (short*)alloc(2097152);
    float* T1   = alloc(4194304);
    short* T1b  = (short*)alloc(2097152);
    float* XLN  = alloc(4194304);
    short* XLNb = (short*)alloc(2097152);
    float* T2   = alloc(4194304);
    short* T2b  = (short*)alloc(2097152);
    float* T3   = alloc(4194304);
    short* HIDb = (short*)alloc(8388608);
    float* D1   = alloc(2097152);
    short* D1b  = (short*)alloc(1048576);
    float* D2   = alloc(1048576);
    short* D2b  = (short*)alloc(524288);
    short* Ebb  = (short*)alloc(262144);
    float* Ebf  = alloc(524288);
    float* MB   = alloc(65536);
    float* VM   = alloc(8192);
    float* MU   = alloc(512);
    float* VARb = alloc(512);
    float* BQKV = alloc(1536);
    float* PS   = alloc(65536);
    float* PQ   = alloc(65536);
    int* IDX  = (int*)alloc(17920);
    int* TOPB = (int*)alloc(4480);
    short* WqkvT = (short*)alloc(393216);
    short* WoT   = (short*)alloc(131072);
    short* ew1T  = (short*)alloc(524288);
    short* ew2T  = (short*)alloc(524288);
    short* dw1T  = (short*)alloc(524288);
    short* dw2T  = (short*)alloc(524288);
    short* W2T   = (short*)alloc(393216);
    (void)ws_size; (void)n_in; (void)in_sizes; (void)out_size;

    static_assert(512 * 65 * 4 == 133120, "");
    hipError_t attr_ok = hipFuncSetAttribute(
        (const void*)msamp_lds_k, hipFuncAttributeMaxDynamicSharedMemorySize, 133120);

    auto gemm128 = [&](const short* A, const short* Bt, const float* bias, const float* res,
                       float* C32, short* C16, int M, int N, int K, int relu, int ldC) {
        gemm128_k<<<(N / 128) * (M / 128), 256, 0, stream>>>(A, Bt, bias, res, C32, C16,
                                                             M, N, K, relu, ldC);
    };
    // N%64==0 GEMMs: 128x64 tile (2 blocks/CU at M=8192) for big M, else 64x64.
    auto gemm64 = [&](const short* A, const short* Bt, const float* bias, const float* res,
                      float* C32, short* C16, int M, int N, int K, int relu, int ldC) {
        if (M >= 8192 && (M & 127) == 0 && (N & 63) == 0) {
            gemm12864_k<<<(N / 64) * (M / 128), 256, 0, stream>>>(A, Bt, bias, res, C32, C16,
                                                                  M, N, K, relu, ldC);
        } else {
            gemm64_k<<<(N / 64) * (M / 64), 256, 0, stream>>>(A, Bt, bias, res, C32, C16,
                                                              M, N, K, relu, ldC);
        }
    };
    auto tr = [&](const float* W, short* Wt, int K, int N) {
        dim3 g(N / 32, K / 32);
        transpose_bf16_k<<<g, 256, 0, stream>>>(W, Wt, K, N);
    };

    auto attn = [&](const short* qinb, const short* kvinb, const float* resp,
                    float* out32, short* out16, int LQ, int LK, int ikey) {
        int Mq = 16 * LQ, Mk = 16 * LK;
        const int ld = 1536;
        float* Qp = QKV;
        float* Kp = QKV + 512;
        float* Vp = QKV + 1024;
        if (qinb == kvinb) {
            gemm128(qinb, WqkvT, BQKV, nullptr, QKV, nullptr, Mq, 1536, 512, 0, ld);
        } else {
            gemm64(qinb, WqkvT, BQKV, nullptr, QKV, nullptr, Mq, 512, 512, 0, ld);
            gemm64(kvinb, WqkvT + 512 * 512, BQKV + 512, nullptr, QKV + 512, nullptr,
                   Mk, 1024, 512, 0, ld);
        }
        int U = imin(5 * iceil_log(LK), LK);
        int u = imin(5 * iceil_log(LQ), LQ);
        unsigned rk0, rk1;
        threefry2x32(0u, 42u, 0u, (unsigned)ikey, rk0, rk1);
        int size = LQ * U;
        ridx_k<<<(size + 255) / 256, 256, 0, stream>>>(rk0, rk1, size, (unsigned)(LK - 1), IDX);
        size_t shbytes = (size_t)LK * 65 * 4;
        if (attr_ok == hipSuccess || shbytes <= 65536) {
            msamp_lds_k<<<16 * 8 * 2, 256, shbytes, stream>>>(Qp, Kp, IDX, MB, LQ, LK, U, ld);
        } else {
            int totM = 16 * 8 * LQ * 4;
            msamp_k<<<(totM + 255) / 256, 256, 0, stream>>>(Qp, Kp, IDX, MB, LQ, LK, U, ld);
        }
        topk_k<<<128, 256, 0, stream>>>(MB, TOPB, LQ, u);
        vmean_k<<<dim3(16, 16), 256, 0, stream>>>(Vp, VM, LK, ld);
        int totC = 16 * LQ * 512;
        ctx_fill_k<<<(totC + 255) / 256, 256, 0, stream>>>(VM, CTXb, LQ, totC);
        attn_flash_k<<<16 * 8 * 2, 256, 0, stream>>>(Qp, Kp, Vp, TOPB, CTXb, LQ, LK, u, ld);
        gemm64(CTXb, WoT, bo, resp, out32, out16, Mq, 512, 512, 0, 512);
    };

    auto encoder = [&](const short* Xb, const float* X, int L, int ikey, float* OUTenc) {
        int M = 16 * L;
        attn(Xb, Xb, X, T1, nullptr, L, L, ikey);
        ln_k<<<M, 256, 0, stream>>>(T1, XLN, XLNb);
        gemm128(XLNb, ew1T, eb1, nullptr, nullptr, HIDb, M, 2048, 512, 1, 2048);
        gemm64(HIDb, ew2T, eb2, XLN, T2, nullptr, M, 512, 2048, 0, 512);
        ln_k<<<M, 256, 0, stream>>>(T2, OUTenc, nullptr);
    };

    auto distill = [&](const float* X, int L, float* OUTd, short* OUTdb) {
        int M = 16 * L;
        int tot = M * 1536;
        xcat_k<<<(tot + 255) / 256, 256, 0, stream>>>(X, HIDb, L, tot);
        gemm64(HIDb, W2T, db, nullptr, CTX, nullptr, M, 512, 1536, 0, 512);
        bnpart_k<<<128, 256, 0, stream>>>(CTX, PS, PQ, M);
        bnfin_k<<<2, 256, 0, stream>>>(PS, PQ, MU, VARb, M);
        int toto = 16 * (L / 2) * 512;
        elu_pool_k<<<(toto + 255) / 256, 256, 0, stream>>>(CTX, MU, VARb, OUTd, OUTdb, L, toto);
    };

    // --- weight conversion (once per launch) ---
    tr(Wq, WqkvT, 512, 512);
    tr(Wk, WqkvT + 512 * 512, 512, 512);
    tr(Wv, WqkvT + 1024 * 512, 512, 512);
    tr(Wo, WoT, 512, 512);
    tr(ew1, ew1T, 512, 2048);
    tr(ew2, ew2T, 2048, 512);
    tr(dw1, dw1T, 512, 2048);
    tr(dw2, dw2T, 2048, 512);
    w2t_k<<<(786432 + 255) / 256, 256, 0, stream>>>(DW, W2T, 786432);
    bcat_k<<<6, 256, 0, stream>>>(bq, bk, bv, BQKV);

    // --- forward ---
    int totPE = 16 * 512 * 512;
    pe_add_k<<<(totPE + 255) / 256, 256, 0, stream>>>(IN, PE, PEb, totPE);

    encoder(PEb, PE, 512, 0, T3); distill(T3, 512, D1, D1b);
    encoder(D1b, D1, 256, 1, T3); distill(T3, 256, D2, D2b);
    encoder(D2b, D2, 128, 2, T3); distill(T3, 128, Ebf, Ebb);

    attn(PEb, PEb, PE, T1, T1b, 512, 512, 3);   // out1 = dec_inp + attn
    attn(T1b, Ebb, T1, T2, T2b, 512, 64, 4);    // out2 = out1 + cross-attn
    gemm128(T2b, dw1T, db1, nullptr, nullptr, HIDb, 8192, 2048, 512, 1, 2048);
    gemm64(HIDb, dw2T, db2, T2, T3, nullptr, 8192, 512, 2048, 0, 512);
    final_k<<<(8192 * 64) / 256, 256, 0, stream>>>(T3, ow, ob, OUT, 8192);
}

// Round 5
// 1562.789 us; speedup vs baseline: 1.0268x; 1.0268x over previous
//
#include <hip/hip_runtime.h>
#include <cstdint>
#include <cmath>

// ---------------------------------------------------------------------------
// Informer forward. Round 20: paired K-steps (2 tiles per barrier interval).
// R18/R19 established: 2-phase counted pipeline works (66->57us) but depth-3
// and bank-deswizzle are both NULL (conflicts 3.1M->0, time flat) -> the
// residual is the per-barrier-step overhead itself (m233: stage+vmcnt+bar is
// ~72% of a 2-phase loop). This round halves the barrier-interval count:
//  - gemm12864_k: 6 tile-buffers (72KB dynamic LDS), per iteration stage
//    PAIR p+2 (6 DMAs), compute tiles 2p,2p+1 (12 ds_read, 16 MFMA),
//    vmcnt(6) [pair p+1 done, pair p+2 in flight], one s_barrier.
//    Per-tile addressing + XOR swizzle reused verbatim from R19 (64B rows
//    keep the 2-way-free bank math; a native 128B-row BK=64 layout would be
//    an unfixable 8-way conflict).
//  - gemm128_k: unchanged from R19 (3-buf depth-2, swizzled).
//  - gemm64_k: unchanged (small-M fallback; also fallback if dyn-LDS attr
//    fails).
// jax.random via threefry2x32 (H2, verified R1).
// ---------------------------------------------------------------------------

#define HD __host__ __device__

typedef short short8 __attribute__((ext_vector_type(8)));
typedef float float4v __attribute__((ext_vector_type(4)));

typedef __attribute__((address_space(1))) const void gvoid;
typedef __attribute__((address_space(3))) void lvoid;

__device__ __forceinline__ void gl_lds16(const void* g, void* l) {
    // async global->LDS DMA, 16B/lane; LDS dest = wave-uniform base + lane*16
    __builtin_amdgcn_global_load_lds((gvoid*)g, (lvoid*)l, 16, 0, 0);
}

__device__ inline short f2bf(float f) {  // RNE
    unsigned u = __float_as_uint(f);
    unsigned r = u + 0x7FFFu + ((u >> 16) & 1u);
    return (short)(r >> 16);
}

HD inline unsigned rotl32(unsigned x, int r) { return (x << r) | (x >> (32 - r)); }
HD inline void tfround(unsigned& x0, unsigned& x1, int r) {
    x0 += x1; x1 = rotl32(x1, r); x1 ^= x0;
}
HD inline void threefry2x32(unsigned k0, unsigned k1, unsigned c0, unsigned c1,
                            unsigned& o0, unsigned& o1) {
    unsigned ks2 = k0 ^ k1 ^ 0x1BD11BDAu;
    unsigned x0 = c0 + k0, x1 = c1 + k1;
    tfround(x0, x1, 13); tfround(x0, x1, 15); tfround(x0, x1, 26); tfround(x0, x1, 6);
    x0 += k1; x1 += ks2 + 1u;
    tfround(x0, x1, 17); tfround(x0, x1, 29); tfround(x0, x1, 16); tfround(x0, x1, 24);
    x0 += ks2; x1 += k0 + 2u;
    tfround(x0, x1, 13); tfround(x0, x1, 15); tfround(x0, x1, 26); tfround(x0, x1, 6);
    x0 += k0; x1 += k1 + 3u;
    tfround(x0, x1, 17); tfround(x0, x1, 29); tfround(x0, x1, 16); tfround(x0, x1, 24);
    x0 += k1; x1 += ks2 + 4u;
    tfround(x0, x1, 13); tfround(x0, x1, 15); tfround(x0, x1, 26); tfround(x0, x1, 6);
    x0 += ks2; x1 += k0 + 5u;
    o0 = x0; o1 = x1;
}

// ---------------------------------------------------------------------------
// Kernels
// ---------------------------------------------------------------------------

// out = in + PE; outb = bf16(out)
__global__ void pe_add_k(const float* __restrict__ in, float* __restrict__ out,
                         short* __restrict__ outb, int total) {
    int t = blockIdx.x * 256 + threadIdx.x;
    if (t >= total) return;
    int d = t % 512;
    int l = (t / 512) % 512;
    float i2 = (float)(d & ~1);
    float div = expf(i2 * (-0.017988946039016f));  // -ln(10000)/512
    float ang = (float)l * div;
    float v = (d & 1) ? cosf(ang) : sinf(ang);
    float r = in[t] + v;
    out[t] = r;
    outb[t] = f2bf(r);
}

// fp32 [K][N] -> bf16 [N][K] via 32x32 LDS tile
__global__ __launch_bounds__(256) void transpose_bf16_k(const float* __restrict__ in,
                                                        short* __restrict__ out, int K, int N) {
    __shared__ float tile[32][33];
    int k0 = blockIdx.y * 32, n0 = blockIdx.x * 32;
    int c = threadIdx.x & 31, r0 = threadIdx.x >> 5;
    for (int rr = r0; rr < 32; rr += 8)
        tile[rr][c] = in[(size_t)(k0 + rr) * N + n0 + c];
    __syncthreads();
    for (int rr = r0; rr < 32; rr += 8)
        out[(size_t)(n0 + rr) * K + k0 + c] = f2bf(tile[c][rr]);
}

// dist_w (O,I,H) -> bf16 W2T[o][h*512+i]
__global__ void w2t_k(const float* __restrict__ dw, short* __restrict__ out, int total) {
    int t = blockIdx.x * 256 + threadIdx.x;
    if (t >= total) return;
    int kk = t % 1536;
    int o = t / 1536;
    int h = kk / 512, i = kk % 512;
    out[t] = f2bf(dw[(size_t)o * 1536 + i * 3 + h]);
}

// concat biases bq|bk|bv -> bqkv[1536]
__global__ void bcat_k(const float* __restrict__ b0, const float* __restrict__ b1,
                       const float* __restrict__ b2, float* __restrict__ out) {
    int t = blockIdx.x * 256 + threadIdx.x;
    if (t >= 1536) return;
    out[t] = (t < 512) ? b0[t] : (t < 1024 ? b1[t - 512] : b2[t - 1024]);
}

__device__ inline void swizzle_bid(int bid, int nbx, int nby, int& bm, int& bn) {
    if ((nby & 7) == 0) {
        int stripe = nby >> 3;
        int x = bid & 7, w = bid >> 3;
        bn = w % nbx;
        bm = x * stripe + w / nbx;
    } else {
        bn = bid % nbx;
        bm = bid / nbx;
    }
}

// bf16 MFMA GEMM, 128x128 tile, BK=32; A bf16 [M][K], Bt bf16 [N][K].
// 3-buffer depth-2 counted pipeline + bank-deswizzled staging/reads. (R19)
__global__ __launch_bounds__(256) void gemm128_k(
    const short* __restrict__ A, const short* __restrict__ Bt,
    const float* __restrict__ bias, const float* __restrict__ res,
    float* __restrict__ C32, short* __restrict__ C16,
    int M, int N, int K, int relu, int ldC) {
    __shared__ short As[3][128 * 32];
    __shared__ short Bs[3][128 * 32];
    int tid = threadIdx.x;
    int wave = tid >> 6, lane = tid & 63;
    int wy = wave >> 1, wx = wave & 1;
    int rl = lane & 15, quad = lane >> 4;
    int bm, bn;
    swizzle_bid(blockIdx.x, N >> 7, M >> 7, bm, bn);
    bm <<= 7; bn <<= 7;

    int srow = (wave << 5) + (lane >> 2);
    int skol = (((lane & 3) ^ ((srow >> 1) & 3)) << 3);
    const short* ga0 = A + (size_t)(bm + srow) * K + skol;
    const short* ga1 = ga0 + (size_t)16 * K;
    const short* gb0 = Bt + (size_t)(bn + srow) * K + skol;
    const short* gb1 = gb0 + (size_t)16 * K;
    int lao = wave << 10;
    int ksw = (quad ^ ((rl >> 1) & 3)) << 3;  // read-side swizzle (same involution)

    float4v acc[4][4];
    #pragma unroll
    for (int i = 0; i < 4; i++)
        #pragma unroll
        for (int j = 0; j < 4; j++) acc[i][j] = (float4v){0.f, 0.f, 0.f, 0.f};

    int nsteps = K >> 5;
    auto stage = [&](int t, int bf) {
        int k0 = t << 5;
        gl_lds16(ga0 + k0, &As[bf][lao]);
        gl_lds16(ga1 + k0, &As[bf][lao + 512]);
        gl_lds16(gb0 + k0, &Bs[bf][lao]);
        gl_lds16(gb1 + k0, &Bs[bf][lao + 512]);
    };
    stage(0, 0);
    stage(1, 1);
    asm volatile("s_waitcnt vmcnt(4)" ::: "memory");
    __builtin_amdgcn_s_barrier();
    __builtin_amdgcn_sched_barrier(0);
    int cur = 0;
    for (int t = 0; t < nsteps; ++t) {
        if (t + 2 < nsteps) {
            int sb = cur + 2; if (sb >= 3) sb -= 3;
            stage(t + 2, sb);
        }
        short8 a[4], b[4];
        #pragma unroll
        for (int i = 0; i < 4; i++)
            a[i] = *(const short8*)&As[cur][(wy * 64 + i * 16 + rl) * 32 + ksw];
        #pragma unroll
        for (int j = 0; j < 4; j++)
            b[j] = *(const short8*)&Bs[cur][(wx * 64 + j * 16 + rl) * 32 + ksw];
        #pragma unroll
        for (int i = 0; i < 4; i++)
            #pragma unroll
            for (int j = 0; j < 4; j++)
                acc[i][j] = __builtin_amdgcn_mfma_f32_16x16x32_bf16(a[i], b[j], acc[i][j], 0, 0, 0);
        if (t + 2 < nsteps) {
            asm volatile("s_waitcnt vmcnt(4)" ::: "memory");
        } else {
            asm volatile("s_waitcnt vmcnt(0)" ::: "memory");
        }
        __builtin_amdgcn_s_barrier();
        __builtin_amdgcn_sched_barrier(0);
        cur = (cur == 2) ? 0 : cur + 1;
    }
    #pragma unroll
    for (int i = 0; i < 4; i++) {
        #pragma unroll
        for (int r = 0; r < 4; r++) {
            int gm = bm + wy * 64 + i * 16 + quad * 4 + r;
            #pragma unroll
            for (int j = 0; j < 4; j++) {
                int gn = bn + wx * 64 + j * 16 + rl;
                float v = acc[i][j][r];
                if (bias) v += bias[gn];
                if (relu) v = fmaxf(v, 0.f);
                if (res) v += res[(size_t)gm * ldC + gn];
                if (C32) C32[(size_t)gm * ldC + gn] = v;
                if (C16) C16[(size_t)gm * ldC + gn] = f2bf(v);
            }
        }
    }
}

// Dynamic LDS for the paired-pipeline GEMM (6 tile-buffers x 12KB = 72KB).
extern __shared__ short gls[];

// 128x64 tile, 4 waves 2x2, per-wave 64x32 output. Paired K-steps:
// 2 BK=32 tiles per barrier interval; 6 buffers, depth-2-pairs counted vmcnt.
__global__ __launch_bounds__(256) void gemm12864_k(
    const short* __restrict__ A, const short* __restrict__ Bt,
    const float* __restrict__ bias, const float* __restrict__ res,
    float* __restrict__ C32, short* __restrict__ C16,
    int M, int N, int K, int relu, int ldC) {
    int tid = threadIdx.x;
    int wave = tid >> 6, lane = tid & 63;
    int wy = wave >> 1, wx = wave & 1;
    int rl = lane & 15, quad = lane >> 4;
    int bm, bn;
    swizzle_bid(blockIdx.x, N >> 6, M >> 7, bm, bn);
    bm <<= 7; bn <<= 6;

    int arow = (wave << 5) + (lane >> 2);   // A: wave covers 32 rows (2 chunks)
    int brow = (wave << 4) + (lane >> 2);   // B: wave covers 16 rows (1 chunk)
    int ska = (((lane & 3) ^ ((arow >> 1) & 3)) << 3);
    int skb = (((lane & 3) ^ ((brow >> 1) & 3)) << 3);
    const short* ga0 = A + (size_t)(bm + arow) * K + ska;
    const short* ga1 = ga0 + (size_t)16 * K;
    const short* gb0 = Bt + (size_t)(bn + brow) * K + skb;
    int lao = wave << 10;   // A per-wave offset within a tile-buffer (shorts)
    int lbo = wave << 9;    // B per-wave offset
    int ksw = (quad ^ ((rl >> 1) & 3)) << 3;

    float4v acc[4][2];
    #pragma unroll
    for (int i = 0; i < 4; i++)
        #pragma unroll
        for (int j = 0; j < 2; j++) acc[i][j] = (float4v){0.f, 0.f, 0.f, 0.f};

    int nt = K >> 5;        // BK=32 tiles (even: K % 64 == 0 guaranteed by host)
    int niter = nt >> 1;    // paired iterations

    // tile-buffer bf in [0,6): A at gls + bf*6144, B at +4096 (shorts)
    auto stageT = [&](int t, int bf) {
        int k0 = t << 5;
        short* Ab = gls + bf * 6144;
        short* Bb = Ab + 4096;
        gl_lds16(ga0 + k0, Ab + lao);
        gl_lds16(ga1 + k0, Ab + lao + 512);
        gl_lds16(gb0 + k0, Bb + lbo);
    };
    auto computeT = [&](int bf) {
        const short* Ab = gls + bf * 6144;
        const short* Bb = Ab + 4096;
        short8 a[4], b[2];
        #pragma unroll
        for (int i = 0; i < 4; i++)
            a[i] = *(const short8*)&Ab[(wy * 64 + i * 16 + rl) * 32 + ksw];
        #pragma unroll
        for (int j = 0; j < 2; j++)
            b[j] = *(const short8*)&Bb[(wx * 32 + j * 16 + rl) * 32 + ksw];
        #pragma unroll
        for (int i = 0; i < 4; i++)
            #pragma unroll
            for (int j = 0; j < 2; j++)
                acc[i][j] = __builtin_amdgcn_mfma_f32_16x16x32_bf16(a[i], b[j], acc[i][j], 0, 0, 0);
    };

    // prologue: pairs 0,1 staged (12 loads); wait pair 0 (6 left in flight)
    stageT(0, 0); stageT(1, 1);
    stageT(2, 2); stageT(3, 3);
    asm volatile("s_waitcnt vmcnt(6)" ::: "memory");
    __builtin_amdgcn_s_barrier();
    __builtin_amdgcn_sched_barrier(0);
    int q = 0;  // pair-slot = p % 3; pair p lives in buffers {2q, 2q+1}
    for (int p = 0; p < niter; ++p) {
        if (p + 2 < niter) {
            int s = q + 2; if (s >= 3) s -= 3;
            int t0 = (p + 2) << 1;
            stageT(t0, 2 * s);
            stageT(t0 + 1, 2 * s + 1);
        }
        computeT(2 * q);
        computeT(2 * q + 1);
        // pair p+1 must be complete; pair p+2 stays in flight
        if (p + 2 < niter) {
            asm volatile("s_waitcnt vmcnt(6)" ::: "memory");
        } else {
            asm volatile("s_waitcnt vmcnt(0)" ::: "memory");
        }
        __builtin_amdgcn_s_barrier();
        __builtin_amdgcn_sched_barrier(0);
        q = (q == 2) ? 0 : q + 1;
    }
    #pragma unroll
    for (int i = 0; i < 4; i++) {
        #pragma unroll
        for (int r = 0; r < 4; r++) {
            int gm = bm + wy * 64 + i * 16 + quad * 4 + r;
            #pragma unroll
            for (int j = 0; j < 2; j++) {
                int gn = bn + wx * 32 + j * 16 + rl;
                float v = acc[i][j][r];
                if (bias) v += bias[gn];
                if (relu) v = fmaxf(v, 0.f);
                if (res) v += res[(size_t)gm * ldC + gn];
                if (C32) C32[(size_t)gm * ldC + gn] = v;
                if (C16) C16[(size_t)gm * ldC + gn] = f2bf(v);
            }
        }
    }
}

// 64x64-tile variant, BK=32. 4 waves, each 16x64. (small-M fallback)
__global__ __launch_bounds__(256) void gemm64_k(
    const short* __restrict__ A, const short* __restrict__ Bt,
    const float* __restrict__ bias, const float* __restrict__ res,
    float* __restrict__ C32, short* __restrict__ C16,
    int M, int N, int K, int relu, int ldC) {
    __shared__ short As[64 * 40];
    __shared__ short Bs[64 * 40];
    int tid = threadIdx.x;
    int wave = tid >> 6, lane = tid & 63;
    int rl = lane & 15, quad = lane >> 4;
    int bm, bn;
    swizzle_bid(blockIdx.x, N >> 6, M >> 6, bm, bn);
    bm <<= 6; bn <<= 6;

    float4v acc[4];
    #pragma unroll
    for (int j = 0; j < 4; j++) acc[j] = (float4v){0.f, 0.f, 0.f, 0.f};

    int row = tid >> 2, seg = tid & 3;
    for (int k0 = 0; k0 < K; k0 += 32) {
        *(float4*)&As[row * 40 + seg * 8] =
            *(const float4*)(A + (size_t)(bm + row) * K + k0 + seg * 8);
        *(float4*)&Bs[row * 40 + seg * 8] =
            *(const float4*)(Bt + (size_t)(bn + row) * K + k0 + seg * 8);
        __syncthreads();
        short8 a = *(const short8*)&As[(wave * 16 + rl) * 40 + quad * 8];
        short8 b[4];
        #pragma unroll
        for (int j = 0; j < 4; j++)
            b[j] = *(const short8*)&Bs[(j * 16 + rl) * 40 + quad * 8];
        #pragma unroll
        for (int j = 0; j < 4; j++)
            acc[j] = __builtin_amdgcn_mfma_f32_16x16x32_bf16(a, b[j], acc[j], 0, 0, 0);
        __syncthreads();
    }
    #pragma unroll
    for (int r = 0; r < 4; r++) {
        int gm = bm + wave * 16 + quad * 4 + r;
        #pragma unroll
        for (int j = 0; j < 4; j++) {
            int gn = bn + j * 16 + rl;
            float v = acc[j][r];
            if (bias) v += bias[gn];
            if (relu) v = fmaxf(v, 0.f);
            if (res) v += res[(size_t)gm * ldC + gn];
            if (C32) C32[(size_t)gm * ldC + gn] = v;
            if (C16) C16[(size_t)gm * ldC + gn] = f2bf(v);
        }
    }
}

// idx[j] = threefry(rkey, (j, j+size)).second & mask   (H2, verified R1)
__global__ void ridx_k(unsigned k0, unsigned k1, int size, unsigned mask, int* __restrict__ idx) {
    int j = blockIdx.x * 256 + threadIdx.x;
    if (j >= size) return;
    unsigned o0, o1;
    threefry2x32(k0, k1, (unsigned)j, (unsigned)(j + size), o0, o1);
    idx[j] = (int)(o1 & mask);
}

// msamp, K-slab in LDS. One block per (b, h, l-half); grid 16*8*2 = 256.
extern __shared__ float kslab[];
__global__ __launch_bounds__(256) void msamp_lds_k(
    const float* __restrict__ Qp, const float* __restrict__ Kp,
    const int* __restrict__ idx, float* __restrict__ Mout,
    int LQ, int LK, int U, int ld) {
    int bid = blockIdx.x;
    int half = bid & 1;
    int bh = bid >> 1;
    int h = bh & 7, b = bh >> 3;
    const float* kbase = Kp + (size_t)b * LK * ld + h * 64;
    for (int t = threadIdx.x; t < LK * 16; t += 256) {
        int r = t >> 4, seg = t & 15;
        float4 v = *(const float4*)(kbase + (size_t)r * ld + seg * 4);
        float* dst = &kslab[r * 65 + seg * 4];
        dst[0] = v.x; dst[1] = v.y; dst[2] = v.z; dst[3] = v.w;
    }
    __syncthreads();
    int halfL = LQ >> 1;
    for (int li = threadIdx.x; li < halfL; li += 256) {
        int l = half * halfL + li;
        const float4* q = (const float4*)(Qp + (size_t)(b * LQ + l) * ld + h * 64);
        float qr[64];
        #pragma unroll
        for (int d4 = 0; d4 < 16; d4++) {
            float4 v = q[d4];
            qr[4 * d4] = v.x; qr[4 * d4 + 1] = v.y; qr[4 * d4 + 2] = v.z; qr[4 * d4 + 3] = v.w;
        }
        const int* ip = idx + l * U;
        float mx = -INFINITY, sm = 0.f;
        for (int s = 0; s < U; s++) {
            const float* kr = &kslab[ip[s] * 65];
            float acc = 0.f;
            #pragma unroll
            for (int d = 0; d < 64; d++) acc += qr[d] * kr[d];
            mx = fmaxf(mx, acc);
            sm += acc;
        }
        Mout[(size_t)bh * LQ + l] = mx - sm / (float)LK;
    }
}

// Fallback msamp if large dynamic-LDS attribute fails.
__global__ void msamp_k(const float* __restrict__ Qp, const float* __restrict__ Kp,
                        const int* __restrict__ idx, float* __restrict__ Mout,
                        int LQ, int LK, int U, int ld) {
    int t = blockIdx.x * 256 + threadIdx.x;
    int total = 16 * 8 * LQ * 4;
    if (t >= total) return;
    int p = t & 3;
    int rest = t >> 2;
    int l = rest % LQ;
    int h = (rest / LQ) & 7;
    int b = rest / (LQ * 8);
    const float4* q = (const float4*)(Qp + ((size_t)(b * LQ + l) * ld + h * 64));
    const float* kb = Kp + ((size_t)b * LK * ld + h * 64);
    float4 qr[16];
    #pragma unroll
    for (int d = 0; d < 16; d++) qr[d] = q[d];
    float mx = -INFINITY, sm = 0.f;
    for (int s = p; s < U; s += 4) {
        const float4* kr = (const float4*)(kb + (size_t)idx[l * U + s] * ld);
        float acc = 0.f;
        #pragma unroll
        for (int d = 0; d < 16; d++) {
            float4 kv = kr[d];
            acc += qr[d].x * kv.x + qr[d].y * kv.y + qr[d].z * kv.z + qr[d].w * kv.w;
        }
        mx = fmaxf(mx, acc);
        sm += acc;
    }
    mx = fmaxf(mx, __shfl_xor(mx, 1));
    mx = fmaxf(mx, __shfl_xor(mx, 2));
    sm += __shfl_xor(sm, 1);
    sm += __shfl_xor(sm, 2);
    if (p == 0)
        Mout[(size_t)((b * 8) + h) * LQ + l] = mx - sm / (float)LK;
}

// Parallel top-u per (b,h): iterative argmax in LDS, lowest-index tie-break.
__global__ __launch_bounds__(256) void topk_k(const float* __restrict__ M,
                                              int* __restrict__ top, int LQ, int u) {
    __shared__ float vals[512];
    __shared__ float rv[256];
    __shared__ int ri[256];
    int bh = blockIdx.x;
    int tid = threadIdx.x;
    const float* m = M + (size_t)bh * LQ;
    for (int l = tid; l < LQ; l += 256) vals[l] = m[l];
    __syncthreads();
    for (int j = 0; j < u; j++) {
        float best = -INFINITY;
        int bi = LQ;
        for (int l = tid; l < LQ; l += 256) {
            float v = vals[l];
            if (v > best) { best = v; bi = l; }
        }
        rv[tid] = best; ri[tid] = bi;
        __syncthreads();
        for (int s = 128; s > 0; s >>= 1) {
            if (tid < s) {
                float v2 = rv[tid + s]; int i2 = ri[tid + s];
                if (v2 > rv[tid] || (v2 == rv[tid] && i2 < ri[tid])) { rv[tid] = v2; ri[tid] = i2; }
            }
            __syncthreads();
        }
        int sel = ri[0];
        if (tid == 0) {
            top[bh * u + j] = sel;
            vals[sel] = -INFINITY;
        }
        __syncthreads();
    }
}

// vm[b,c] = mean over l of V[b,l,c]; parallel over l. grid (16 c-chunks, 16 b).
__global__ __launch_bounds__(256) void vmean_k(const float* __restrict__ Vp,
                                               float* __restrict__ vm, int LK, int ld) {
    __shared__ float red[8][33];
    int b = blockIdx.y;
    int c0 = blockIdx.x * 32;
    int ci = threadIdx.x & 31, g = threadIdx.x >> 5;
    const float* base = Vp + (size_t)b * LK * ld + c0 + ci;
    float s = 0.f;
    for (int l = g; l < LK; l += 8) s += base[(size_t)l * ld];
    red[g][ci] = s;
    __syncthreads();
    if (threadIdx.x < 32) {
        float t = 0.f;
        #pragma unroll
        for (int g2 = 0; g2 < 8; g2++) t += red[g2][threadIdx.x];
        vm[b * 512 + c0 + threadIdx.x] = t / (float)LK;
    }
}

// ctxb[b,l,c] = bf16(vm[b,c])
__global__ void ctx_fill_k(const float* __restrict__ vm, short* __restrict__ ctxb,
                           int LQ, int total) {
    int t = blockIdx.x * 256 + threadIdx.x;
    if (t >= total) return;
    int c = t % 512;
    int b = t / (512 * LQ);
    ctxb[t] = f2bf(vm[b * 512 + c]);
}

// Flash-style ProbSparse attention: one block per (b, h, u-half), 256 threads.
__global__ __launch_bounds__(256) void attn_flash_k(
    const float* __restrict__ Qp, const float* __restrict__ Kp, const float* __restrict__ Vp,
    const int* __restrict__ top, short* __restrict__ ctxb, int LQ, int LK, int u, int ld) {
    __shared__ float qs[18][64];
    __shared__ int ls[18];
    __shared__ float kv[64][65];
    __shared__ float sc[18][512];
    int bid = blockIdx.x;
    int chunk = bid & 1;  // 2 chunks per (b,h)
    int h = (bid >> 1) & 7;
    int b = bid >> 4;
    int CH = (u + 1) >> 1;
    int r0 = chunk * CH;
    int nr = min(CH, u - r0);
    int tid = threadIdx.x;
    int wave = tid >> 6, lane = tid & 63;

    if (tid < nr) ls[tid] = top[((b * 8) + h) * u + r0 + tid];
    __syncthreads();
    for (int t = tid; t < nr * 16; t += 256) {
        int r = t >> 4, seg = t & 15;
        float4 v = *(const float4*)(Qp + ((size_t)(b * LQ + ls[r])) * ld + h * 64 + seg * 4);
        float* dst = &qs[r][seg * 4];
        dst[0] = v.x; dst[1] = v.y; dst[2] = v.z; dst[3] = v.w;
    }

    int ntile = LK >> 6;
    const float* kbase = Kp + ((size_t)b * LK) * ld + h * 64;
    for (int T = 0; T < ntile; T++) {
        __syncthreads();
        #pragma unroll
        for (int it = 0; it < 4; it++) {
            int t = tid + it * 256;
            int kk = t >> 4, seg = t & 15;
            float4 v = *(const float4*)(kbase + (size_t)(T * 64 + kk) * ld + seg * 4);
            float* dst = &kv[kk][seg * 4];
            dst[0] = v.x; dst[1] = v.y; dst[2] = v.z; dst[3] = v.w;
        }
        __syncthreads();
        for (int p = tid; p < nr * 64; p += 256) {
            int r = p >> 6, kk = p & 63;
            float acc = 0.f;
            #pragma unroll
            for (int d = 0; d < 64; d++) acc += qs[r][d] * kv[kk][d];
            sc[r][T * 64 + kk] = acc * 0.125f;  // 1/sqrt(64)
        }
    }
    __syncthreads();
    for (int r = wave; r < nr; r += 4) {
        float mx = -INFINITY;
        for (int k = lane; k < LK; k += 64) mx = fmaxf(mx, sc[r][k]);
        #pragma unroll
        for (int o = 32; o > 0; o >>= 1) mx = fmaxf(mx, __shfl_xor(mx, o));
        float s = 0.f;
        for (int k = lane; k < LK; k += 64) {
            float e = expf(sc[r][k] - mx);
            sc[r][k] = e;
            s += e;
        }
        #pragma unroll
        for (int o = 32; o > 0; o >>= 1) s += __shfl_xor(s, o);
        float inv = 1.0f / s;
        for (int k = lane; k < LK; k += 64) sc[r][k] *= inv;
    }
    float acc[5];
    #pragma unroll
    for (int i = 0; i < 5; i++) acc[i] = 0.f;
    const float* vbase = Vp + ((size_t)b * LK) * ld + h * 64;
    for (int T = 0; T < ntile; T++) {
        __syncthreads();
        #pragma unroll
        for (int it = 0; it < 4; it++) {
            int t = tid + it * 256;
            int kk = t >> 4, seg = t & 15;
            float4 v = *(const float4*)(vbase + (size_t)(T * 64 + kk) * ld + seg * 4);
            float* dst = &kv[kk][seg * 4];
            dst[0] = v.x; dst[1] = v.y; dst[2] = v.z; dst[3] = v.w;
        }
        __syncthreads();
        int ri = 0;
        for (int r = wave; r < nr; r += 4, ri++) {
            float a = 0.f;
            #pragma unroll
            for (int kk = 0; kk < 64; kk++) a += sc[r][T * 64 + kk] * kv[kk][lane];
            acc[ri] += a;
        }
    }
    int ri = 0;
    for (int r = wave; r < nr; r += 4, ri++)
        ctxb[((size_t)(b * LQ + ls[r])) * 512 + h * 64 + lane] = f2bf(acc[ri]);
}

// per-row layer norm, D=512; optional bf16 mirror
__global__ __launch_bounds__(256) void ln_k(const float* __restrict__ in,
                                            float* __restrict__ out, short* __restrict__ outb) {
    __shared__ float red[256];
    int r = blockIdx.x;
    int tid = threadIdx.x;
    const float* x = in + (size_t)r * 512;
    float a = x[tid], b = x[tid + 256];
    red[tid] = a + b;
    __syncthreads();
    for (int s = 128; s > 0; s >>= 1) {
        if (tid < s) red[tid] += red[tid + s];
        __syncthreads();
    }
    float mu = red[0] / 512.f;
    __syncthreads();
    float d1 = a - mu, d2 = b - mu;
    red[tid] = d1 * d1 + d2 * d2;
    __syncthreads();
    for (int s = 128; s > 0; s >>= 1) {
        if (tid < s) red[tid] += red[tid + s];
        __syncthreads();
    }
    float inv = 1.0f / sqrtf(red[0] / 512.f + 1e-5f);
    float v1 = d1 * inv, v2 = d2 * inv;
    out[(size_t)r * 512 + tid] = v1;
    out[(size_t)r * 512 + tid + 256] = v2;
    if (outb) {
        outb[(size_t)r * 512 + tid] = f2bf(v1);
        outb[(size_t)r * 512 + tid + 256] = f2bf(v2);
    }
}

// circular-pad im2col -> bf16
__global__ void xcat_k(const float* __restrict__ x, short* __restrict__ xc, int L, int total) {
    int t = blockIdx.x * 256 + threadIdx.x;
    if (t >= total) return;
    int i = t % 512;
    int h = (t / 512) % 3;
    int bt = t / 1536;
    int tt = bt % L;
    int b = bt / L;
    int src = (tt + h - 1 + L) % L;
    xc[t] = f2bf(x[(size_t)(b * L + src) * 512 + i]);
}

// bn stage 1: per-chunk per-channel sum/sumsq, coalesced row reads. grid=128.
__global__ __launch_bounds__(256) void bnpart_k(const float* __restrict__ y,
                                                float* __restrict__ ps, float* __restrict__ pq,
                                                int rows) {
    int chunk = blockIdx.x;
    int rpc = rows >> 7;
    int r0 = chunk * rpc;
    int tid = threadIdx.x;
    float s0 = 0.f, s1 = 0.f, q0 = 0.f, q1 = 0.f;
    for (int r = r0; r < r0 + rpc; r++) {
        float a = y[(size_t)r * 512 + tid];
        float b = y[(size_t)r * 512 + tid + 256];
        s0 += a; q0 += a * a;
        s1 += b; q1 += b * b;
    }
    ps[chunk * 512 + tid] = s0;
    ps[chunk * 512 + tid + 256] = s1;
    pq[chunk * 512 + tid] = q0;
    pq[chunk * 512 + tid + 256] = q1;
}

// bn stage 2: mu = s/n; var = q/n - mu^2.
__global__ void bnfin_k(const float* __restrict__ ps, const float* __restrict__ pq,
                        float* __restrict__ mu, float* __restrict__ var, int rows) {
    int o = blockIdx.x * 256 + threadIdx.x;
    if (o >= 512) return;
    float s = 0.f, q = 0.f;
    for (int c = 0; c < 128; c++) {
        s += ps[c * 512 + o];
        q += pq[c * 512 + o];
    }
    float m = s / (float)rows;
    mu[o] = m;
    var[o] = q / (float)rows - m * m;
}

// normalize -> max-pool(3,2,pad1) -> elu; writes fp32 + bf16 mirror
__global__ void elu_pool_k(const float* __restrict__ y, const float* __restrict__ mu,
                           const float* __restrict__ var, float* __restrict__ out,
                           short* __restrict__ outb, int L, int total) {
    int t = blockIdx.x * 256 + threadIdx.x;
    if (t >= total) return;
    int o = t % 512;
    int tp = (t / 512) % (L / 2);
    int b = t / (512 * (L / 2));
    float mm = mu[o];
    float inv = 1.0f / sqrtf(var[o] + 1e-5f);
    float m = -INFINITY;
    #pragma unroll
    for (int dt = 0; dt < 3; dt++) {
        int tt = 2 * tp - 1 + dt;
        if (tt < 0 || tt >= L) continue;
        float v = (y[(size_t)(b * L + tt) * 512 + o] - mm) * inv;
        m = fmaxf(m, v);
    }
    float r = m > 0.f ? m : expm1f(m);
    out[t] = r;
    outb[t] = f2bf(r);
}

// out[r] = dot(x[r,:512], w) + b
__global__ void final_k(const float* __restrict__ x, const float* __restrict__ w,
                        const float* __restrict__ bb, float* __restrict__ out, int rows) {
    int gid = blockIdx.x * 256 + threadIdx.x;
    int wid = gid >> 6;
    int lane = gid & 63;
    if (wid >= rows) return;
    const float* xr = x + (size_t)wid * 512;
    float acc = 0.f;
    for (int k = lane; k < 512; k += 64) acc += xr[k] * w[k];
    for (int off = 32; off > 0; off >>= 1) acc += __shfl_down(acc, off);
    if (lane == 0) out[wid] = acc + bb[0];
}

// ---------------------------------------------------------------------------
// Host driver
// ---------------------------------------------------------------------------

static inline int iceil_log(int L) { return (int)ceil(log((double)L)); }
static inline int imin(int a, int b) { return a < b ? a : b; }

extern "C" void kernel_launch(void* const* d_in, const int* in_sizes, int n_in,
                              void* d_out, int out_size, void* d_ws, size_t ws_size,
                              hipStream_t stream) {
    const float* IN  = (const float*)d_in[0];
    const float* Wq  = (const float*)d_in[1];
    const float* bq  = (const float*)d_in[2];
    const float* Wk  = (const float*)d_in[3];
    const float* bk  = (const float*)d_in[4];
    const float* Wv  = (const float*)d_in[5];
    const float* bv  = (const float*)d_in[6];
    const float* Wo  = (const float*)d_in[7];
    const float* bo  = (const float*)d_in[8];
    const float* ew1 = (const float*)d_in[9];
    const float* eb1 = (const float*)d_in[10];
    const float* ew2 = (const float*)d_in[11];
    const float* eb2 = (const float*)d_in[12];
    const float* dw1 = (const float*)d_in[13];
    const float* db1 = (const float*)d_in[14];
    const float* dw2 = (const float*)d_in[15];
    const float* db2 = (const float*)d_in[16];
    const float* DW  = (const float*)d_in[17];
    const float* db  = (const float*)d_in[18];
    const float* ow  = (const float*)d_in[19];
    const float* ob  = (const float*)d_in[20];
    float* OUT = (float*)d_out;

    float* ws = (float*)d_ws;
    size_t off = 0;
    auto alloc = [&](size_t n) { float* p = ws + off; off += n; return p; };
    float* PE   = alloc(4194304);
    short* PEb  = (short*)alloc(2097152);
    float* QKV  = alloc(12582912);
    float* CTX  = alloc(4194304);
    short* CTXb = (short*)alloc(2097152);
    float* T1   = alloc(4194304);
    short* T1b  = (short*)alloc(2097152);
    float* XLN  = alloc(4194304);
    short* XLNb = (short*)alloc(2097152);
    float* T2   = alloc(4194304);
    short* T2b  = (short*)alloc(2097152);
    float* T3   = alloc(4194304);
    short* HIDb = (short*)alloc(8388608);
    float* D1   = alloc(2097152);
    short* D1b  = (short*)alloc(1048576);
    float* D2   = alloc(1048576);
    short* D2b  = (short*)alloc(524288);
    short* Ebb  = (short*)alloc(262144);
    float* Ebf  = alloc(524288);
    float* MB   = alloc(65536);
    float* VM   = alloc(8192);
    float* MU   = alloc(512);
    float* VARb = alloc(512);
    float* BQKV = alloc(1536);
    float* PS   = alloc(65536);
    float* PQ   = alloc(65536);
    int* IDX  = (int*)alloc(17920);
    int* TOPB = (int*)alloc(4480);
    short* WqkvT = (short*)alloc(393216);
    short* WoT   = (short*)alloc(131072);
    short* ew1T  = (short*)alloc(524288);
    short* ew2T  = (short*)alloc(524288);
    short* dw1T  = (short*)alloc(524288);
    short* dw2T  = (short*)alloc(524288);
    short* W2T   = (short*)alloc(393216);
    (void)ws_size; (void)n_in; (void)in_sizes; (void)out_size;

    static_assert(512 * 65 * 4 == 133120, "");
    hipError_t attr_ok = hipFuncSetAttribute(
        (const void*)msamp_lds_k, hipFuncAttributeMaxDynamicSharedMemorySize, 133120);
    // 72KB dynamic LDS for the paired-pipeline GEMM
    hipError_t attr_g = hipFuncSetAttribute(
        (const void*)gemm12864_k, hipFuncAttributeMaxDynamicSharedMemorySize, 73728);

    auto gemm128 = [&](const short* A, const short* Bt, const float* bias, const float* res,
                       float* C32, short* C16, int M, int N, int K, int relu, int ldC) {
        gemm128_k<<<(N / 128) * (M / 128), 256, 0, stream>>>(A, Bt, bias, res, C32, C16,
                                                             M, N, K, relu, ldC);
    };
    // N%64==0 GEMMs: paired-pipeline 128x64 tile for big M, else 64x64.
    auto gemm64 = [&](const short* A, const short* Bt, const float* bias, const float* res,
                      float* C32, short* C16, int M, int N, int K, int relu, int ldC) {
        if (attr_g == hipSuccess && M >= 8192 && (M & 127) == 0 && (N & 63) == 0 &&
            (K & 63) == 0) {
            gemm12864_k<<<(N / 64) * (M / 128), 256, 73728, stream>>>(A, Bt, bias, res,
                                                                      C32, C16, M, N, K,
                                                                      relu, ldC);
        } else {
            gemm64_k<<<(N / 64) * (M / 64), 256, 0, stream>>>(A, Bt, bias, res, C32, C16,
                                                              M, N, K, relu, ldC);
        }
    };
    auto tr = [&](const float* W, short* Wt, int K, int N) {
        dim3 g(N / 32, K / 32);
        transpose_bf16_k<<<g, 256, 0, stream>>>(W, Wt, K, N);
    };

    auto attn = [&](const short* qinb, const short* kvinb, const float* resp,
                    float* out32, short* out16, int LQ, int LK, int ikey) {
        int Mq = 16 * LQ, Mk = 16 * LK;
        const int ld = 1536;
        float* Qp = QKV;
        float* Kp = QKV + 512;
        float* Vp = QKV + 1024;
        if (qinb == kvinb) {
            gemm128(qinb, WqkvT, BQKV, nullptr, QKV, nullptr, Mq, 1536, 512, 0, ld);
        } else {
            gemm64(qinb, WqkvT, BQKV, nullptr, QKV, nullptr, Mq, 512, 512, 0, ld);
            gemm64(kvinb, WqkvT + 512 * 512, BQKV + 512, nullptr, QKV + 512, nullptr,
                   Mk, 1024, 512, 0, ld);
        }
        int U = imin(5 * iceil_log(LK), LK);
        int u = imin(5 * iceil_log(LQ), LQ);
        unsigned rk0, rk1;
        threefry2x32(0u, 42u, 0u, (unsigned)ikey, rk0, rk1);
        int size = LQ * U;
        ridx_k<<<(size + 255) / 256, 256, 0, stream>>>(rk0, rk1, size, (unsigned)(LK - 1), IDX);
        size_t shbytes = (size_t)LK * 65 * 4;
        if (attr_ok == hipSuccess || shbytes <= 65536) {
            msamp_lds_k<<<16 * 8 * 2, 256, shbytes, stream>>>(Qp, Kp, IDX, MB, LQ, LK, U, ld);
        } else {
            int totM = 16 * 8 * LQ * 4;
            msamp_k<<<(totM + 255) / 256, 256, 0, stream>>>(Qp, Kp, IDX, MB, LQ, LK, U, ld);
        }
        topk_k<<<128, 256, 0, stream>>>(MB, TOPB, LQ, u);
        vmean_k<<<dim3(16, 16), 256, 0, stream>>>(Vp, VM, LK, ld);
        int totC = 16 * LQ * 512;
        ctx_fill_k<<<(totC + 255) / 256, 256, 0, stream>>>(VM, CTXb, LQ, totC);
        attn_flash_k<<<16 * 8 * 2, 256, 0, stream>>>(Qp, Kp, Vp, TOPB, CTXb, LQ, LK, u, ld);
        gemm64(CTXb, WoT, bo, resp, out32, out16, Mq, 512, 512, 0, 512);
    };

    auto encoder = [&](const short* Xb, const float* X, int L, int ikey, float* OUTenc) {
        int M = 16 * L;
        attn(Xb, Xb, X, T1, nullptr, L, L, ikey);
        ln_k<<<M, 256, 0, stream>>>(T1, XLN, XLNb);
        gemm128(XLNb, ew1T, eb1, nullptr, nullptr, HIDb, M, 2048, 512, 1, 2048);
        gemm64(HIDb, ew2T, eb2, XLN, T2, nullptr, M, 512, 2048, 0, 512);
        ln_k<<<M, 256, 0, stream>>>(T2, OUTenc, nullptr);
    };

    auto distill = [&](const float* X, int L, float* OUTd, short* OUTdb) {
        int M = 16 * L;
        int tot = M * 1536;
        xcat_k<<<(tot + 255) / 256, 256, 0, stream>>>(X, HIDb, L, tot);
        gemm64(HIDb, W2T, db, nullptr, CTX, nullptr, M, 512, 1536, 0, 512);
        bnpart_k<<<128, 256, 0, stream>>>(CTX, PS, PQ, M);
        bnfin_k<<<2, 256, 0, stream>>>(PS, PQ, MU, VARb, M);
        int toto = 16 * (L / 2) * 512;
        elu_pool_k<<<(toto + 255) / 256, 256, 0, stream>>>(CTX, MU, VARb, OUTd, OUTdb, L, toto);
    };

    // --- weight conversion (once per launch) ---
    tr(Wq, WqkvT, 512, 512);
    tr(Wk, WqkvT + 512 * 512, 512, 512);
    tr(Wv, WqkvT + 1024 * 512, 512, 512);
    tr(Wo, WoT, 512, 512);
    tr(ew1, ew1T, 512, 2048);
    tr(ew2, ew2T, 2048, 512);
    tr(dw1, dw1T, 512, 2048);
    tr(dw2, dw2T, 2048, 512);
    w2t_k<<<(786432 + 255) / 256, 256, 0, stream>>>(DW, W2T, 786432);
    bcat_k<<<6, 256, 0, stream>>>(bq, bk, bv, BQKV);

    // --- forward ---
    int totPE = 16 * 512 * 512;
    pe_add_k<<<(totPE + 255) / 256, 256, 0, stream>>>(IN, PE, PEb, totPE);

    encoder(PEb, PE, 512, 0, T3); distill(T3, 512, D1, D1b);
    encoder(D1b, D1, 256, 1, T3); distill(T3, 256, D2, D2b);
    encoder(D2b, D2, 128, 2, T3); distill(T3, 128, Ebf, Ebb);

    attn(PEb, PEb, PE, T1, T1b, 512, 512, 3);   // out1 = dec_inp + attn
    attn(T1b, Ebb, T1, T2, T2b, 512, 64, 4);    // out2 = out1 + cross-attn
    gemm128(T2b, dw1T, db1, nullptr, nullptr, HIDb, 8192, 2048, 512, 1, 2048);
    gemm64(HIDb, dw2T, db2, T2, T3, nullptr, 8192, 512, 2048, 0, 512);
    final_k<<<(8192 * 64) / 256, 256, 0, stream>>>(T3, ow, ob, OUT, 8192);
}

// Round 6
// 1500.329 us; speedup vs baseline: 1.0695x; 1.0416x over previous
//
#include <hip/hip_runtime.h>
#include <cstdint>
#include <cmath>

// ---------------------------------------------------------------------------
// Informer forward. Round 21: spread proven wins to the unmeasured mass.
//  - gemm64_k: upgraded to the R18-proven 2-phase DMA pipeline (stage(t+1)
//    before compute(t), vmcnt(0)+s_barrier after MFMAs) + R19 XOR deswizzle.
//    Was the last reg-staged drain loop (~100-170us across enc2/enc3/distill/
//    crossKV sites).
//  - pe_add/ctx_fill/xcat vectorized (G13): 8 elems/thread, float4x2 loads,
//    short8 stores; pe_add uses sincosf (halves transcendental count).
//  - gemm128_k (R19 3-buf depth-2) and gemm12864_k (R20 paired) UNCHANGED —
//    they are the measured top-5; attribution for this round is end-to-end
//    minus their (expected-flat) rows.
// jax.random via threefry2x32 (H2, verified R1).
// ---------------------------------------------------------------------------

#define HD __host__ __device__

typedef short short8 __attribute__((ext_vector_type(8)));
typedef float float4v __attribute__((ext_vector_type(4)));

typedef __attribute__((address_space(1))) const void gvoid;
typedef __attribute__((address_space(3))) void lvoid;

__device__ __forceinline__ void gl_lds16(const void* g, void* l) {
    // async global->LDS DMA, 16B/lane; LDS dest = wave-uniform base + lane*16
    __builtin_amdgcn_global_load_lds((gvoid*)g, (lvoid*)l, 16, 0, 0);
}

__device__ inline short f2bf(float f) {  // RNE
    unsigned u = __float_as_uint(f);
    unsigned r = u + 0x7FFFu + ((u >> 16) & 1u);
    return (short)(r >> 16);
}

HD inline unsigned rotl32(unsigned x, int r) { return (x << r) | (x >> (32 - r)); }
HD inline void tfround(unsigned& x0, unsigned& x1, int r) {
    x0 += x1; x1 = rotl32(x1, r); x1 ^= x0;
}
HD inline void threefry2x32(unsigned k0, unsigned k1, unsigned c0, unsigned c1,
                            unsigned& o0, unsigned& o1) {
    unsigned ks2 = k0 ^ k1 ^ 0x1BD11BDAu;
    unsigned x0 = c0 + k0, x1 = c1 + k1;
    tfround(x0, x1, 13); tfround(x0, x1, 15); tfround(x0, x1, 26); tfround(x0, x1, 6);
    x0 += k1; x1 += ks2 + 1u;
    tfround(x0, x1, 17); tfround(x0, x1, 29); tfround(x0, x1, 16); tfround(x0, x1, 24);
    x0 += ks2; x1 += k0 + 2u;
    tfround(x0, x1, 13); tfround(x0, x1, 15); tfround(x0, x1, 26); tfround(x0, x1, 6);
    x0 += k0; x1 += k1 + 3u;
    tfround(x0, x1, 17); tfround(x0, x1, 29); tfround(x0, x1, 16); tfround(x0, x1, 24);
    x0 += k1; x1 += ks2 + 4u;
    tfround(x0, x1, 13); tfround(x0, x1, 15); tfround(x0, x1, 26); tfround(x0, x1, 6);
    x0 += ks2; x1 += k0 + 5u;
    o0 = x0; o1 = x1;
}

// ---------------------------------------------------------------------------
// Kernels
// ---------------------------------------------------------------------------

// out = in + PE; outb = bf16(out). 8 elems/thread, sincosf per (sin,cos) pair.
__global__ void pe_add_k(const float* __restrict__ in, float* __restrict__ out,
                         short* __restrict__ outb, int total8) {
    int t = blockIdx.x * 256 + threadIdx.x;
    if (t >= total8) return;
    int e = t * 8;
    int d0 = e & 511;
    int l = (e >> 9) & 511;
    float4 v0 = *(const float4*)(in + e);
    float4 v1 = *(const float4*)(in + e + 4);
    float vin[8] = {v0.x, v0.y, v0.z, v0.w, v1.x, v1.y, v1.z, v1.w};
    float r[8];
    #pragma unroll
    for (int p = 0; p < 4; p++) {
        int d = d0 + 2 * p;
        float div = expf((float)d * (-0.017988946039016f));  // -ln(10000)/512
        float ang = (float)l * div;
        float s, c;
        sincosf(ang, &s, &c);
        r[2 * p] = vin[2 * p] + s;
        r[2 * p + 1] = vin[2 * p + 1] + c;
    }
    *(float4*)(out + e) = (float4){r[0], r[1], r[2], r[3]};
    *(float4*)(out + e + 4) = (float4){r[4], r[5], r[6], r[7]};
    short8 ob;
    #pragma unroll
    for (int p = 0; p < 8; p++) ob[p] = f2bf(r[p]);
    *(short8*)(outb + e) = ob;
}

// fp32 [K][N] -> bf16 [N][K] via 32x32 LDS tile
__global__ __launch_bounds__(256) void transpose_bf16_k(const float* __restrict__ in,
                                                        short* __restrict__ out, int K, int N) {
    __shared__ float tile[32][33];
    int k0 = blockIdx.y * 32, n0 = blockIdx.x * 32;
    int c = threadIdx.x & 31, r0 = threadIdx.x >> 5;
    for (int rr = r0; rr < 32; rr += 8)
        tile[rr][c] = in[(size_t)(k0 + rr) * N + n0 + c];
    __syncthreads();
    for (int rr = r0; rr < 32; rr += 8)
        out[(size_t)(n0 + rr) * K + k0 + c] = f2bf(tile[c][rr]);
}

// dist_w (O,I,H) -> bf16 W2T[o][h*512+i]
__global__ void w2t_k(const float* __restrict__ dw, short* __restrict__ out, int total) {
    int t = blockIdx.x * 256 + threadIdx.x;
    if (t >= total) return;
    int kk = t % 1536;
    int o = t / 1536;
    int h = kk / 512, i = kk % 512;
    out[t] = f2bf(dw[(size_t)o * 1536 + i * 3 + h]);
}

// concat biases bq|bk|bv -> bqkv[1536]
__global__ void bcat_k(const float* __restrict__ b0, const float* __restrict__ b1,
                       const float* __restrict__ b2, float* __restrict__ out) {
    int t = blockIdx.x * 256 + threadIdx.x;
    if (t >= 1536) return;
    out[t] = (t < 512) ? b0[t] : (t < 1024 ? b1[t - 512] : b2[t - 1024]);
}

__device__ inline void swizzle_bid(int bid, int nbx, int nby, int& bm, int& bn) {
    if ((nby & 7) == 0) {
        int stripe = nby >> 3;
        int x = bid & 7, w = bid >> 3;
        bn = w % nbx;
        bm = x * stripe + w / nbx;
    } else {
        bn = bid % nbx;
        bm = bid / nbx;
    }
}

// bf16 MFMA GEMM, 128x128 tile, BK=32; A bf16 [M][K], Bt bf16 [N][K].
// 3-buffer depth-2 counted pipeline + bank-deswizzled staging/reads. (R19)
__global__ __launch_bounds__(256) void gemm128_k(
    const short* __restrict__ A, const short* __restrict__ Bt,
    const float* __restrict__ bias, const float* __restrict__ res,
    float* __restrict__ C32, short* __restrict__ C16,
    int M, int N, int K, int relu, int ldC) {
    __shared__ short As[3][128 * 32];
    __shared__ short Bs[3][128 * 32];
    int tid = threadIdx.x;
    int wave = tid >> 6, lane = tid & 63;
    int wy = wave >> 1, wx = wave & 1;
    int rl = lane & 15, quad = lane >> 4;
    int bm, bn;
    swizzle_bid(blockIdx.x, N >> 7, M >> 7, bm, bn);
    bm <<= 7; bn <<= 7;

    int srow = (wave << 5) + (lane >> 2);
    int skol = (((lane & 3) ^ ((srow >> 1) & 3)) << 3);
    const short* ga0 = A + (size_t)(bm + srow) * K + skol;
    const short* ga1 = ga0 + (size_t)16 * K;
    const short* gb0 = Bt + (size_t)(bn + srow) * K + skol;
    const short* gb1 = gb0 + (size_t)16 * K;
    int lao = wave << 10;
    int ksw = (quad ^ ((rl >> 1) & 3)) << 3;  // read-side swizzle (same involution)

    float4v acc[4][4];
    #pragma unroll
    for (int i = 0; i < 4; i++)
        #pragma unroll
        for (int j = 0; j < 4; j++) acc[i][j] = (float4v){0.f, 0.f, 0.f, 0.f};

    int nsteps = K >> 5;
    auto stage = [&](int t, int bf) {
        int k0 = t << 5;
        gl_lds16(ga0 + k0, &As[bf][lao]);
        gl_lds16(ga1 + k0, &As[bf][lao + 512]);
        gl_lds16(gb0 + k0, &Bs[bf][lao]);
        gl_lds16(gb1 + k0, &Bs[bf][lao + 512]);
    };
    stage(0, 0);
    stage(1, 1);
    asm volatile("s_waitcnt vmcnt(4)" ::: "memory");
    __builtin_amdgcn_s_barrier();
    __builtin_amdgcn_sched_barrier(0);
    int cur = 0;
    for (int t = 0; t < nsteps; ++t) {
        if (t + 2 < nsteps) {
            int sb = cur + 2; if (sb >= 3) sb -= 3;
            stage(t + 2, sb);
        }
        short8 a[4], b[4];
        #pragma unroll
        for (int i = 0; i < 4; i++)
            a[i] = *(const short8*)&As[cur][(wy * 64 + i * 16 + rl) * 32 + ksw];
        #pragma unroll
        for (int j = 0; j < 4; j++)
            b[j] = *(const short8*)&Bs[cur][(wx * 64 + j * 16 + rl) * 32 + ksw];
        #pragma unroll
        for (int i = 0; i < 4; i++)
            #pragma unroll
            for (int j = 0; j < 4; j++)
                acc[i][j] = __builtin_amdgcn_mfma_f32_16x16x32_bf16(a[i], b[j], acc[i][j], 0, 0, 0);
        if (t + 2 < nsteps) {
            asm volatile("s_waitcnt vmcnt(4)" ::: "memory");
        } else {
            asm volatile("s_waitcnt vmcnt(0)" ::: "memory");
        }
        __builtin_amdgcn_s_barrier();
        __builtin_amdgcn_sched_barrier(0);
        cur = (cur == 2) ? 0 : cur + 1;
    }
    #pragma unroll
    for (int i = 0; i < 4; i++) {
        #pragma unroll
        for (int r = 0; r < 4; r++) {
            int gm = bm + wy * 64 + i * 16 + quad * 4 + r;
            #pragma unroll
            for (int j = 0; j < 4; j++) {
                int gn = bn + wx * 64 + j * 16 + rl;
                float v = acc[i][j][r];
                if (bias) v += bias[gn];
                if (relu) v = fmaxf(v, 0.f);
                if (res) v += res[(size_t)gm * ldC + gn];
                if (C32) C32[(size_t)gm * ldC + gn] = v;
                if (C16) C16[(size_t)gm * ldC + gn] = f2bf(v);
            }
        }
    }
}

// Dynamic LDS for the paired-pipeline GEMM (6 tile-buffers x 12KB = 72KB).
extern __shared__ short gls[];

// 128x64 tile, 4 waves 2x2, per-wave 64x32 output. Paired K-steps:
// 2 BK=32 tiles per barrier interval; 6 buffers, depth-2-pairs counted vmcnt.
__global__ __launch_bounds__(256) void gemm12864_k(
    const short* __restrict__ A, const short* __restrict__ Bt,
    const float* __restrict__ bias, const float* __restrict__ res,
    float* __restrict__ C32, short* __restrict__ C16,
    int M, int N, int K, int relu, int ldC) {
    int tid = threadIdx.x;
    int wave = tid >> 6, lane = tid & 63;
    int wy = wave >> 1, wx = wave & 1;
    int rl = lane & 15, quad = lane >> 4;
    int bm, bn;
    swizzle_bid(blockIdx.x, N >> 6, M >> 7, bm, bn);
    bm <<= 7; bn <<= 6;

    int arow = (wave << 5) + (lane >> 2);   // A: wave covers 32 rows (2 chunks)
    int brow = (wave << 4) + (lane >> 2);   // B: wave covers 16 rows (1 chunk)
    int ska = (((lane & 3) ^ ((arow >> 1) & 3)) << 3);
    int skb = (((lane & 3) ^ ((brow >> 1) & 3)) << 3);
    const short* ga0 = A + (size_t)(bm + arow) * K + ska;
    const short* ga1 = ga0 + (size_t)16 * K;
    const short* gb0 = Bt + (size_t)(bn + brow) * K + skb;
    int lao = wave << 10;   // A per-wave offset within a tile-buffer (shorts)
    int lbo = wave << 9;    // B per-wave offset
    int ksw = (quad ^ ((rl >> 1) & 3)) << 3;

    float4v acc[4][2];
    #pragma unroll
    for (int i = 0; i < 4; i++)
        #pragma unroll
        for (int j = 0; j < 2; j++) acc[i][j] = (float4v){0.f, 0.f, 0.f, 0.f};

    int nt = K >> 5;        // BK=32 tiles (even: K % 64 == 0 guaranteed by host)
    int niter = nt >> 1;    // paired iterations

    // tile-buffer bf in [0,6): A at gls + bf*6144, B at +4096 (shorts)
    auto stageT = [&](int t, int bf) {
        int k0 = t << 5;
        short* Ab = gls + bf * 6144;
        short* Bb = Ab + 4096;
        gl_lds16(ga0 + k0, Ab + lao);
        gl_lds16(ga1 + k0, Ab + lao + 512);
        gl_lds16(gb0 + k0, Bb + lbo);
    };
    auto computeT = [&](int bf) {
        const short* Ab = gls + bf * 6144;
        const short* Bb = Ab + 4096;
        short8 a[4], b[2];
        #pragma unroll
        for (int i = 0; i < 4; i++)
            a[i] = *(const short8*)&Ab[(wy * 64 + i * 16 + rl) * 32 + ksw];
        #pragma unroll
        for (int j = 0; j < 2; j++)
            b[j] = *(const short8*)&Bb[(wx * 32 + j * 16 + rl) * 32 + ksw];
        #pragma unroll
        for (int i = 0; i < 4; i++)
            #pragma unroll
            for (int j = 0; j < 2; j++)
                acc[i][j] = __builtin_amdgcn_mfma_f32_16x16x32_bf16(a[i], b[j], acc[i][j], 0, 0, 0);
    };

    // prologue: pairs 0,1 staged (12 loads); wait pair 0 (6 left in flight)
    stageT(0, 0); stageT(1, 1);
    stageT(2, 2); stageT(3, 3);
    asm volatile("s_waitcnt vmcnt(6)" ::: "memory");
    __builtin_amdgcn_s_barrier();
    __builtin_amdgcn_sched_barrier(0);
    int q = 0;  // pair-slot = p % 3; pair p lives in buffers {2q, 2q+1}
    for (int p = 0; p < niter; ++p) {
        if (p + 2 < niter) {
            int s = q + 2; if (s >= 3) s -= 3;
            int t0 = (p + 2) << 1;
            stageT(t0, 2 * s);
            stageT(t0 + 1, 2 * s + 1);
        }
        computeT(2 * q);
        computeT(2 * q + 1);
        // pair p+1 must be complete; pair p+2 stays in flight
        if (p + 2 < niter) {
            asm volatile("s_waitcnt vmcnt(6)" ::: "memory");
        } else {
            asm volatile("s_waitcnt vmcnt(0)" ::: "memory");
        }
        __builtin_amdgcn_s_barrier();
        __builtin_amdgcn_sched_barrier(0);
        q = (q == 2) ? 0 : q + 1;
    }
    #pragma unroll
    for (int i = 0; i < 4; i++) {
        #pragma unroll
        for (int r = 0; r < 4; r++) {
            int gm = bm + wy * 64 + i * 16 + quad * 4 + r;
            #pragma unroll
            for (int j = 0; j < 2; j++) {
                int gn = bn + wx * 32 + j * 16 + rl;
                float v = acc[i][j][r];
                if (bias) v += bias[gn];
                if (relu) v = fmaxf(v, 0.f);
                if (res) v += res[(size_t)gm * ldC + gn];
                if (C32) C32[(size_t)gm * ldC + gn] = v;
                if (C16) C16[(size_t)gm * ldC + gn] = f2bf(v);
            }
        }
    }
}

// 64x64-tile variant, BK=32. 4 waves, each 16x64.
// R21: 2-phase DMA pipeline (R18-proven) + XOR deswizzle (R19-proven).
__global__ __launch_bounds__(256) void gemm64_k(
    const short* __restrict__ A, const short* __restrict__ Bt,
    const float* __restrict__ bias, const float* __restrict__ res,
    float* __restrict__ C32, short* __restrict__ C16,
    int M, int N, int K, int relu, int ldC) {
    __shared__ short As[2][64 * 32];
    __shared__ short Bs[2][64 * 32];
    int tid = threadIdx.x;
    int wave = tid >> 6, lane = tid & 63;
    int rl = lane & 15, quad = lane >> 4;
    int bm, bn;
    swizzle_bid(blockIdx.x, N >> 6, M >> 6, bm, bn);
    bm <<= 6; bn <<= 6;

    // staging: wave w covers rows w*16..w*16+15 (1 DMA chunk each for A,B);
    // lane -> row = lane/4, k-seg = lane&3, global seg XOR ((row>>1)&3).
    int srow = (wave << 4) + (lane >> 2);
    int skol = (((lane & 3) ^ ((srow >> 1) & 3)) << 3);
    const short* ga = A + (size_t)(bm + srow) * K + skol;
    const short* gb = Bt + (size_t)(bn + srow) * K + skol;
    int lof = wave << 9;  // 16 rows x 32 shorts
    int ksw = (quad ^ ((rl >> 1) & 3)) << 3;

    float4v acc[4];
    #pragma unroll
    for (int j = 0; j < 4; j++) acc[j] = (float4v){0.f, 0.f, 0.f, 0.f};

    int nsteps = K >> 5;
    auto stage = [&](int t, int bf) {
        int k0 = t << 5;
        gl_lds16(ga + k0, &As[bf][lof]);
        gl_lds16(gb + k0, &Bs[bf][lof]);
    };
    stage(0, 0);
    asm volatile("s_waitcnt vmcnt(0)" ::: "memory");
    __builtin_amdgcn_s_barrier();
    __builtin_amdgcn_sched_barrier(0);
    int cur = 0;
    for (int t = 0; t < nsteps; ++t) {
        if (t + 1 < nsteps) stage(t + 1, cur ^ 1);
        short8 a = *(const short8*)&As[cur][(wave * 16 + rl) * 32 + ksw];
        short8 b[4];
        #pragma unroll
        for (int j = 0; j < 4; j++)
            b[j] = *(const short8*)&Bs[cur][(j * 16 + rl) * 32 + ksw];
        #pragma unroll
        for (int j = 0; j < 4; j++)
            acc[j] = __builtin_amdgcn_mfma_f32_16x16x32_bf16(a, b[j], acc[j], 0, 0, 0);
        asm volatile("s_waitcnt vmcnt(0)" ::: "memory");
        __builtin_amdgcn_s_barrier();
        __builtin_amdgcn_sched_barrier(0);
        cur ^= 1;
    }
    #pragma unroll
    for (int r = 0; r < 4; r++) {
        int gm = bm + wave * 16 + quad * 4 + r;
        #pragma unroll
        for (int j = 0; j < 4; j++) {
            int gn = bn + j * 16 + rl;
            float v = acc[j][r];
            if (bias) v += bias[gn];
            if (relu) v = fmaxf(v, 0.f);
            if (res) v += res[(size_t)gm * ldC + gn];
            if (C32) C32[(size_t)gm * ldC + gn] = v;
            if (C16) C16[(size_t)gm * ldC + gn] = f2bf(v);
        }
    }
}

// idx[j] = threefry(rkey, (j, j+size)).second & mask   (H2, verified R1)
__global__ void ridx_k(unsigned k0, unsigned k1, int size, unsigned mask, int* __restrict__ idx) {
    int j = blockIdx.x * 256 + threadIdx.x;
    if (j >= size) return;
    unsigned o0, o1;
    threefry2x32(k0, k1, (unsigned)j, (unsigned)(j + size), o0, o1);
    idx[j] = (int)(o1 & mask);
}

// msamp, K-slab in LDS. One block per (b, h, l-half); grid 16*8*2 = 256.
extern __shared__ float kslab[];
__global__ __launch_bounds__(256) void msamp_lds_k(
    const float* __restrict__ Qp, const float* __restrict__ Kp,
    const int* __restrict__ idx, float* __restrict__ Mout,
    int LQ, int LK, int U, int ld) {
    int bid = blockIdx.x;
    int half = bid & 1;
    int bh = bid >> 1;
    int h = bh & 7, b = bh >> 3;
    const float* kbase = Kp + (size_t)b * LK * ld + h * 64;
    for (int t = threadIdx.x; t < LK * 16; t += 256) {
        int r = t >> 4, seg = t & 15;
        float4 v = *(const float4*)(kbase + (size_t)r * ld + seg * 4);
        float* dst = &kslab[r * 65 + seg * 4];
        dst[0] = v.x; dst[1] = v.y; dst[2] = v.z; dst[3] = v.w;
    }
    __syncthreads();
    int halfL = LQ >> 1;
    for (int li = threadIdx.x; li < halfL; li += 256) {
        int l = half * halfL + li;
        const float4* q = (const float4*)(Qp + (size_t)(b * LQ + l) * ld + h * 64);
        float qr[64];
        #pragma unroll
        for (int d4 = 0; d4 < 16; d4++) {
            float4 v = q[d4];
            qr[4 * d4] = v.x; qr[4 * d4 + 1] = v.y; qr[4 * d4 + 2] = v.z; qr[4 * d4 + 3] = v.w;
        }
        const int* ip = idx + l * U;
        float mx = -INFINITY, sm = 0.f;
        for (int s = 0; s < U; s++) {
            const float* kr = &kslab[ip[s] * 65];
            float acc = 0.f;
            #pragma unroll
            for (int d = 0; d < 64; d++) acc += qr[d] * kr[d];
            mx = fmaxf(mx, acc);
            sm += acc;
        }
        Mout[(size_t)bh * LQ + l] = mx - sm / (float)LK;
    }
}

// Fallback msamp if large dynamic-LDS attribute fails.
__global__ void msamp_k(const float* __restrict__ Qp, const float* __restrict__ Kp,
                        const int* __restrict__ idx, float* __restrict__ Mout,
                        int LQ, int LK, int U, int ld) {
    int t = blockIdx.x * 256 + threadIdx.x;
    int total = 16 * 8 * LQ * 4;
    if (t >= total) return;
    int p = t & 3;
    int rest = t >> 2;
    int l = rest % LQ;
    int h = (rest / LQ) & 7;
    int b = rest / (LQ * 8);
    const float4* q = (const float4*)(Qp + ((size_t)(b * LQ + l) * ld + h * 64));
    const float* kb = Kp + ((size_t)b * LK * ld + h * 64);
    float4 qr[16];
    #pragma unroll
    for (int d = 0; d < 16; d++) qr[d] = q[d];
    float mx = -INFINITY, sm = 0.f;
    for (int s = p; s < U; s += 4) {
        const float4* kr = (const float4*)(kb + (size_t)idx[l * U + s] * ld);
        float acc = 0.f;
        #pragma unroll
        for (int d = 0; d < 16; d++) {
            float4 kv = kr[d];
            acc += qr[d].x * kv.x + qr[d].y * kv.y + qr[d].z * kv.z + qr[d].w * kv.w;
        }
        mx = fmaxf(mx, acc);
        sm += acc;
    }
    mx = fmaxf(mx, __shfl_xor(mx, 1));
    mx = fmaxf(mx, __shfl_xor(mx, 2));
    sm += __shfl_xor(sm, 1);
    sm += __shfl_xor(sm, 2);
    if (p == 0)
        Mout[(size_t)((b * 8) + h) * LQ + l] = mx - sm / (float)LK;
}

// Parallel top-u per (b,h): iterative argmax in LDS, lowest-index tie-break.
__global__ __launch_bounds__(256) void topk_k(const float* __restrict__ M,
                                              int* __restrict__ top, int LQ, int u) {
    __shared__ float vals[512];
    __shared__ float rv[256];
    __shared__ int ri[256];
    int bh = blockIdx.x;
    int tid = threadIdx.x;
    const float* m = M + (size_t)bh * LQ;
    for (int l = tid; l < LQ; l += 256) vals[l] = m[l];
    __syncthreads();
    for (int j = 0; j < u; j++) {
        float best = -INFINITY;
        int bi = LQ;
        for (int l = tid; l < LQ; l += 256) {
            float v = vals[l];
            if (v > best) { best = v; bi = l; }
        }
        rv[tid] = best; ri[tid] = bi;
        __syncthreads();
        for (int s = 128; s > 0; s >>= 1) {
            if (tid < s) {
                float v2 = rv[tid + s]; int i2 = ri[tid + s];
                if (v2 > rv[tid] || (v2 == rv[tid] && i2 < ri[tid])) { rv[tid] = v2; ri[tid] = i2; }
            }
            __syncthreads();
        }
        int sel = ri[0];
        if (tid == 0) {
            top[bh * u + j] = sel;
            vals[sel] = -INFINITY;
        }
        __syncthreads();
    }
}

// vm[b,c] = mean over l of V[b,l,c]; parallel over l. grid (16 c-chunks, 16 b).
__global__ __launch_bounds__(256) void vmean_k(const float* __restrict__ Vp,
                                               float* __restrict__ vm, int LK, int ld) {
    __shared__ float red[8][33];
    int b = blockIdx.y;
    int c0 = blockIdx.x * 32;
    int ci = threadIdx.x & 31, g = threadIdx.x >> 5;
    const float* base = Vp + (size_t)b * LK * ld + c0 + ci;
    float s = 0.f;
    for (int l = g; l < LK; l += 8) s += base[(size_t)l * ld];
    red[g][ci] = s;
    __syncthreads();
    if (threadIdx.x < 32) {
        float t = 0.f;
        #pragma unroll
        for (int g2 = 0; g2 < 8; g2++) t += red[g2][threadIdx.x];
        vm[b * 512 + c0 + threadIdx.x] = t / (float)LK;
    }
}

// ctxb[b,l,c] = bf16(vm[b,c]); 8 elems/thread.
__global__ void ctx_fill_k(const float* __restrict__ vm, short* __restrict__ ctxb,
                           int LQ, int total8) {
    int t = blockIdx.x * 256 + threadIdx.x;
    if (t >= total8) return;
    int e = t * 8;
    int c = e & 511;
    int b = e / (LQ << 9);
    float4 v0 = *(const float4*)(vm + b * 512 + c);
    float4 v1 = *(const float4*)(vm + b * 512 + c + 4);
    float vv[8] = {v0.x, v0.y, v0.z, v0.w, v1.x, v1.y, v1.z, v1.w};
    short8 ob;
    #pragma unroll
    for (int p = 0; p < 8; p++) ob[p] = f2bf(vv[p]);
    *(short8*)(ctxb + e) = ob;
}

// Flash-style ProbSparse attention: one block per (b, h, u-half), 256 threads.
__global__ __launch_bounds__(256) void attn_flash_k(
    const float* __restrict__ Qp, const float* __restrict__ Kp, const float* __restrict__ Vp,
    const int* __restrict__ top, short* __restrict__ ctxb, int LQ, int LK, int u, int ld) {
    __shared__ float qs[18][64];
    __shared__ int ls[18];
    __shared__ float kv[64][65];
    __shared__ float sc[18][512];
    int bid = blockIdx.x;
    int chunk = bid & 1;  // 2 chunks per (b,h)
    int h = (bid >> 1) & 7;
    int b = bid >> 4;
    int CH = (u + 1) >> 1;
    int r0 = chunk * CH;
    int nr = min(CH, u - r0);
    int tid = threadIdx.x;
    int wave = tid >> 6, lane = tid & 63;

    if (tid < nr) ls[tid] = top[((b * 8) + h) * u + r0 + tid];
    __syncthreads();
    for (int t = tid; t < nr * 16; t += 256) {
        int r = t >> 4, seg = t & 15;
        float4 v = *(const float4*)(Qp + ((size_t)(b * LQ + ls[r])) * ld + h * 64 + seg * 4);
        float* dst = &qs[r][seg * 4];
        dst[0] = v.x; dst[1] = v.y; dst[2] = v.z; dst[3] = v.w;
    }

    int ntile = LK >> 6;
    const float* kbase = Kp + ((size_t)b * LK) * ld + h * 64;
    for (int T = 0; T < ntile; T++) {
        __syncthreads();
        #pragma unroll
        for (int it = 0; it < 4; it++) {
            int t = tid + it * 256;
            int kk = t >> 4, seg = t & 15;
            float4 v = *(const float4*)(kbase + (size_t)(T * 64 + kk) * ld + seg * 4);
            float* dst = &kv[kk][seg * 4];
            dst[0] = v.x; dst[1] = v.y; dst[2] = v.z; dst[3] = v.w;
        }
        __syncthreads();
        for (int p = tid; p < nr * 64; p += 256) {
            int r = p >> 6, kk = p & 63;
            float acc = 0.f;
            #pragma unroll
            for (int d = 0; d < 64; d++) acc += qs[r][d] * kv[kk][d];
            sc[r][T * 64 + kk] = acc * 0.125f;  // 1/sqrt(64)
        }
    }
    __syncthreads();
    for (int r = wave; r < nr; r += 4) {
        float mx = -INFINITY;
        for (int k = lane; k < LK; k += 64) mx = fmaxf(mx, sc[r][k]);
        #pragma unroll
        for (int o = 32; o > 0; o >>= 1) mx = fmaxf(mx, __shfl_xor(mx, o));
        float s = 0.f;
        for (int k = lane; k < LK; k += 64) {
            float e = expf(sc[r][k] - mx);
            sc[r][k] = e;
            s += e;
        }
        #pragma unroll
        for (int o = 32; o > 0; o >>= 1) s += __shfl_xor(s, o);
        float inv = 1.0f / s;
        for (int k = lane; k < LK; k += 64) sc[r][k] *= inv;
    }
    float acc[5];
    #pragma unroll
    for (int i = 0; i < 5; i++) acc[i] = 0.f;
    const float* vbase = Vp + ((size_t)b * LK) * ld + h * 64;
    for (int T = 0; T < ntile; T++) {
        __syncthreads();
        #pragma unroll
        for (int it = 0; it < 4; it++) {
            int t = tid + it * 256;
            int kk = t >> 4, seg = t & 15;
            float4 v = *(const float4*)(vbase + (size_t)(T * 64 + kk) * ld + seg * 4);
            float* dst = &kv[kk][seg * 4];
            dst[0] = v.x; dst[1] = v.y; dst[2] = v.z; dst[3] = v.w;
        }
        __syncthreads();
        int ri = 0;
        for (int r = wave; r < nr; r += 4, ri++) {
            float a = 0.f;
            #pragma unroll
            for (int kk = 0; kk < 64; kk++) a += sc[r][T * 64 + kk] * kv[kk][lane];
            acc[ri] += a;
        }
    }
    int ri = 0;
    for (int r = wave; r < nr; r += 4, ri++)
        ctxb[((size_t)(b * LQ + ls[r])) * 512 + h * 64 + lane] = f2bf(acc[ri]);
}

// per-row layer norm, D=512; optional bf16 mirror
__global__ __launch_bounds__(256) void ln_k(const float* __restrict__ in,
                                            float* __restrict__ out, short* __restrict__ outb) {
    __shared__ float red[256];
    int r = blockIdx.x;
    int tid = threadIdx.x;
    const float* x = in + (size_t)r * 512;
    float a = x[tid], b = x[tid + 256];
    red[tid] = a + b;
    __syncthreads();
    for (int s = 128; s > 0; s >>= 1) {
        if (tid < s) red[tid] += red[tid + s];
        __syncthreads();
    }
    float mu = red[0] / 512.f;
    __syncthreads();
    float d1 = a - mu, d2 = b - mu;
    red[tid] = d1 * d1 + d2 * d2;
    __syncthreads();
    for (int s = 128; s > 0; s >>= 1) {
        if (tid < s) red[tid] += red[tid + s];
        __syncthreads();
    }
    float inv = 1.0f / sqrtf(red[0] / 512.f + 1e-5f);
    float v1 = d1 * inv, v2 = d2 * inv;
    out[(size_t)r * 512 + tid] = v1;
    out[(size_t)r * 512 + tid + 256] = v2;
    if (outb) {
        outb[(size_t)r * 512 + tid] = f2bf(v1);
        outb[(size_t)r * 512 + tid + 256] = f2bf(v2);
    }
}

// circular-pad im2col -> bf16; 8 elems/thread.
__global__ void xcat_k(const float* __restrict__ x, short* __restrict__ xc, int L, int total8) {
    int t = blockIdx.x * 256 + threadIdx.x;
    if (t >= total8) return;
    int e = t * 8;
    int i = e & 511;
    int q = e >> 9;
    int h = q % 3;
    int bt = q / 3;
    int tt = bt % L;
    int b = bt / L;
    int src = (tt + h - 1 + L) % L;
    const float* s = x + (size_t)(b * L + src) * 512 + i;
    float4 v0 = *(const float4*)s;
    float4 v1 = *(const float4*)(s + 4);
    float vv[8] = {v0.x, v0.y, v0.z, v0.w, v1.x, v1.y, v1.z, v1.w};
    short8 ob;
    #pragma unroll
    for (int p = 0; p < 8; p++) ob[p] = f2bf(vv[p]);
    *(short8*)(xc + e) = ob;
}

// bn stage 1: per-chunk per-channel sum/sumsq, coalesced row reads. grid=128.
__global__ __launch_bounds__(256) void bnpart_k(const float* __restrict__ y,
                                                float* __restrict__ ps, float* __restrict__ pq,
                                                int rows) {
    int chunk = blockIdx.x;
    int rpc = rows >> 7;
    int r0 = chunk * rpc;
    int tid = threadIdx.x;
    float s0 = 0.f, s1 = 0.f, q0 = 0.f, q1 = 0.f;
    for (int r = r0; r < r0 + rpc; r++) {
        float a = y[(size_t)r * 512 + tid];
        float b = y[(size_t)r * 512 + tid + 256];
        s0 += a; q0 += a * a;
        s1 += b; q1 += b * b;
    }
    ps[chunk * 512 + tid] = s0;
    ps[chunk * 512 + tid + 256] = s1;
    pq[chunk * 512 + tid] = q0;
    pq[chunk * 512 + tid + 256] = q1;
}

// bn stage 2: mu = s/n; var = q/n - mu^2.
__global__ void bnfin_k(const float* __restrict__ ps, const float* __restrict__ pq,
                        float* __restrict__ mu, float* __restrict__ var, int rows) {
    int o = blockIdx.x * 256 + threadIdx.x;
    if (o >= 512) return;
    float s = 0.f, q = 0.f;
    for (int c = 0; c < 128; c++) {
        s += ps[c * 512 + o];
        q += pq[c * 512 + o];
    }
    float m = s / (float)rows;
    mu[o] = m;
    var[o] = q / (float)rows - m * m;
}

// normalize -> max-pool(3,2,pad1) -> elu; writes fp32 + bf16 mirror
__global__ void elu_pool_k(const float* __restrict__ y, const float* __restrict__ mu,
                           const float* __restrict__ var, float* __restrict__ out,
                           short* __restrict__ outb, int L, int total) {
    int t = blockIdx.x * 256 + threadIdx.x;
    if (t >= total) return;
    int o = t % 512;
    int tp = (t / 512) % (L / 2);
    int b = t / (512 * (L / 2));
    float mm = mu[o];
    float inv = 1.0f / sqrtf(var[o] + 1e-5f);
    float m = -INFINITY;
    #pragma unroll
    for (int dt = 0; dt < 3; dt++) {
        int tt = 2 * tp - 1 + dt;
        if (tt < 0 || tt >= L) continue;
        float v = (y[(size_t)(b * L + tt) * 512 + o] - mm) * inv;
        m = fmaxf(m, v);
    }
    float r = m > 0.f ? m : expm1f(m);
    out[t] = r;
    outb[t] = f2bf(r);
}

// out[r] = dot(x[r,:512], w) + b
__global__ void final_k(const float* __restrict__ x, const float* __restrict__ w,
                        const float* __restrict__ bb, float* __restrict__ out, int rows) {
    int gid = blockIdx.x * 256 + threadIdx.x;
    int wid = gid >> 6;
    int lane = gid & 63;
    if (wid >= rows) return;
    const float* xr = x + (size_t)wid * 512;
    float acc = 0.f;
    for (int k = lane; k < 512; k += 64) acc += xr[k] * w[k];
    for (int off = 32; off > 0; off >>= 1) acc += __shfl_down(acc, off);
    if (lane == 0) out[wid] = acc + bb[0];
}

// ---------------------------------------------------------------------------
// Host driver
// ---------------------------------------------------------------------------

static inline int iceil_log(int L) { return (int)ceil(log((double)L)); }
static inline int imin(int a, int b) { return a < b ? a : b; }

extern "C" void kernel_launch(void* const* d_in, const int* in_sizes, int n_in,
                              void* d_out, int out_size, void* d_ws, size_t ws_size,
                              hipStream_t stream) {
    const float* IN  = (const float*)d_in[0];
    const float* Wq  = (const float*)d_in[1];
    const float* bq  = (const float*)d_in[2];
    const float* Wk  = (const float*)d_in[3];
    const float* bk  = (const float*)d_in[4];
    const float* Wv  = (const float*)d_in[5];
    const float* bv  = (const float*)d_in[6];
    const float* Wo  = (const float*)d_in[7];
    const float* bo  = (const float*)d_in[8];
    const float* ew1 = (const float*)d_in[9];
    const float* eb1 = (const float*)d_in[10];
    const float* ew2 = (const float*)d_in[11];
    const float* eb2 = (const float*)d_in[12];
    const float* dw1 = (const float*)d_in[13];
    const float* db1 = (const float*)d_in[14];
    const float* dw2 = (const float*)d_in[15];
    const float* db2 = (const float*)d_in[16];
    const float* DW  = (const float*)d_in[17];
    const float* db  = (const float*)d_in[18];
    const float* ow  = (const float*)d_in[19];
    const float* ob  = (const float*)d_in[20];
    float* OUT = (float*)d_out;

    float* ws = (float*)d_ws;
    size_t off = 0;
    auto alloc = [&](size_t n) { float* p = ws + off; off += n; return p; };
    float* PE   = alloc(4194304);
    short* PEb  = (short*)alloc(2097152);
    float* QKV  = alloc(12582912);
    float* CTX  = alloc(4194304);
    short* CTXb = (short*)alloc(2097152);
    float* T1   = alloc(4194304);
    short* T1b  = (short*)alloc(2097152);
    float* XLN  = alloc(4194304);
    short* XLNb = (short*)alloc(2097152);
    float* T2   = alloc(4194304);
    short* T2b  = (short*)alloc(2097152);
    float* T3   = alloc(4194304);
    short* HIDb = (short*)alloc(8388608);
    float* D1   = alloc(2097152);
    short* D1b  = (short*)alloc(1048576);
    float* D2   = alloc(1048576);
    short* D2b  = (short*)alloc(524288);
    short* Ebb  = (short*)alloc(262144);
    float* Ebf  = alloc(524288);
    float* MB   = alloc(65536);
    float* VM   = alloc(8192);
    float* MU   = alloc(512);
    float* VARb = alloc(512);
    float* BQKV = alloc(1536);
    float* PS   = alloc(65536);
    float* PQ   = alloc(65536);
    int* IDX  = (int*)alloc(17920);
    int* TOPB = (int*)alloc(4480);
    short* WqkvT = (short*)alloc(393216);
    short* WoT   = (short*)alloc(131072);
    short* ew1T  = (short*)alloc(524288);
    short* ew2T  = (short*)alloc(524288);
    short* dw1T  = (short*)alloc(524288);
    short* dw2T  = (short*)alloc(524288);
    short* W2T   = (short*)alloc(393216);
    (void)ws_size; (void)n_in; (void)in_sizes; (void)out_size;

    static_assert(512 * 65 * 4 == 133120, "");
    hipError_t attr_ok = hipFuncSetAttribute(
        (const void*)msamp_lds_k, hipFuncAttributeMaxDynamicSharedMemorySize, 133120);
    // 72KB dynamic LDS for the paired-pipeline GEMM
    hipError_t attr_g = hipFuncSetAttribute(
        (const void*)gemm12864_k, hipFuncAttributeMaxDynamicSharedMemorySize, 73728);

    auto gemm128 = [&](const short* A, const short* Bt, const float* bias, const float* res,
                       float* C32, short* C16, int M, int N, int K, int relu, int ldC) {
        gemm128_k<<<(N / 128) * (M / 128), 256, 0, stream>>>(A, Bt, bias, res, C32, C16,
                                                             M, N, K, relu, ldC);
    };
    // N%64==0 GEMMs: paired-pipeline 128x64 tile for big M, else 64x64.
    auto gemm64 = [&](const short* A, const short* Bt, const float* bias, const float* res,
                      float* C32, short* C16, int M, int N, int K, int relu, int ldC) {
        if (attr_g == hipSuccess && M >= 8192 && (M & 127) == 0 && (N & 63) == 0 &&
            (K & 63) == 0) {
            gemm12864_k<<<(N / 64) * (M / 128), 256, 73728, stream>>>(A, Bt, bias, res,
                                                                      C32, C16, M, N, K,
                                                                      relu, ldC);
        } else {
            gemm64_k<<<(N / 64) * (M / 64), 256, 0, stream>>>(A, Bt, bias, res, C32, C16,
                                                              M, N, K, relu, ldC);
        }
    };
    auto tr = [&](const float* W, short* Wt, int K, int N) {
        dim3 g(N / 32, K / 32);
        transpose_bf16_k<<<g, 256, 0, stream>>>(W, Wt, K, N);
    };

    auto attn = [&](const short* qinb, const short* kvinb, const float* resp,
                    float* out32, short* out16, int LQ, int LK, int ikey) {
        int Mq = 16 * LQ, Mk = 16 * LK;
        const int ld = 1536;
        float* Qp = QKV;
        float* Kp = QKV + 512;
        float* Vp = QKV + 1024;
        if (qinb == kvinb) {
            gemm128(qinb, WqkvT, BQKV, nullptr, QKV, nullptr, Mq, 1536, 512, 0, ld);
        } else {
            gemm64(qinb, WqkvT, BQKV, nullptr, QKV, nullptr, Mq, 512, 512, 0, ld);
            gemm64(kvinb, WqkvT + 512 * 512, BQKV + 512, nullptr, QKV + 512, nullptr,
                   Mk, 1024, 512, 0, ld);
        }
        int U = imin(5 * iceil_log(LK), LK);
        int u = imin(5 * iceil_log(LQ), LQ);
        unsigned rk0, rk1;
        threefry2x32(0u, 42u, 0u, (unsigned)ikey, rk0, rk1);
        int size = LQ * U;
        ridx_k<<<(size + 255) / 256, 256, 0, stream>>>(rk0, rk1, size, (unsigned)(LK - 1), IDX);
        size_t shbytes = (size_t)LK * 65 * 4;
        if (attr_ok == hipSuccess || shbytes <= 65536) {
            msamp_lds_k<<<16 * 8 * 2, 256, shbytes, stream>>>(Qp, Kp, IDX, MB, LQ, LK, U, ld);
        } else {
            int totM = 16 * 8 * LQ * 4;
            msamp_k<<<(totM + 255) / 256, 256, 0, stream>>>(Qp, Kp, IDX, MB, LQ, LK, U, ld);
        }
        topk_k<<<128, 256, 0, stream>>>(MB, TOPB, LQ, u);
        vmean_k<<<dim3(16, 16), 256, 0, stream>>>(Vp, VM, LK, ld);
        int totC8 = 16 * LQ * 512 / 8;
        ctx_fill_k<<<(totC8 + 255) / 256, 256, 0, stream>>>(VM, CTXb, LQ, totC8);
        attn_flash_k<<<16 * 8 * 2, 256, 0, stream>>>(Qp, Kp, Vp, TOPB, CTXb, LQ, LK, u, ld);
        gemm64(CTXb, WoT, bo, resp, out32, out16, Mq, 512, 512, 0, 512);
    };

    auto encoder = [&](const short* Xb, const float* X, int L, int ikey, float* OUTenc) {
        int M = 16 * L;
        attn(Xb, Xb, X, T1, nullptr, L, L, ikey);
        ln_k<<<M, 256, 0, stream>>>(T1, XLN, XLNb);
        gemm128(XLNb, ew1T, eb1, nullptr, nullptr, HIDb, M, 2048, 512, 1, 2048);
        gemm64(HIDb, ew2T, eb2, XLN, T2, nullptr, M, 512, 2048, 0, 512);
        ln_k<<<M, 256, 0, stream>>>(T2, OUTenc, nullptr);
    };

    auto distill = [&](const float* X, int L, float* OUTd, short* OUTdb) {
        int M = 16 * L;
        int tot8 = M * 1536 / 8;
        xcat_k<<<(tot8 + 255) / 256, 256, 0, stream>>>(X, HIDb, L, tot8);
        gemm64(HIDb, W2T, db, nullptr, CTX, nullptr, M, 512, 1536, 0, 512);
        bnpart_k<<<128, 256, 0, stream>>>(CTX, PS, PQ, M);
        bnfin_k<<<2, 256, 0, stream>>>(PS, PQ, MU, VARb, M);
        int toto = 16 * (L / 2) * 512;
        elu_pool_k<<<(toto + 255) / 256, 256, 0, stream>>>(CTX, MU, VARb, OUTd, OUTdb, L, toto);
    };

    // --- weight conversion (once per launch) ---
    tr(Wq, WqkvT, 512, 512);
    tr(Wk, WqkvT + 512 * 512, 512, 512);
    tr(Wv, WqkvT + 1024 * 512, 512, 512);
    tr(Wo, WoT, 512, 512);
    tr(ew1, ew1T, 512, 2048);
    tr(ew2, ew2T, 2048, 512);
    tr(dw1, dw1T, 512, 2048);
    tr(dw2, dw2T, 2048, 512);
    w2t_k<<<(786432 + 255) / 256, 256, 0, stream>>>(DW, W2T, 786432);
    bcat_k<<<6, 256, 0, stream>>>(bq, bk, bv, BQKV);

    // --- forward ---
    int totPE8 = 16 * 512 * 512 / 8;
    pe_add_k<<<(totPE8 + 255) / 256, 256, 0, stream>>>(IN, PE, PEb, totPE8);

    encoder(PEb, PE, 512, 0, T3); distill(T3, 512, D1, D1b);
    encoder(D1b, D1, 256, 1, T3); distill(T3, 256, D2, D2b);
    encoder(D2b, D2, 128, 2, T3); distill(T3, 128, Ebf, Ebb);

    attn(PEb, PEb, PE, T1, T1b, 512, 512, 3);   // out1 = dec_inp + attn
    attn(T1b, Ebb, T1, T2, T2b, 512, 64, 4);    // out2 = out1 + cross-attn
    gemm128(T2b, dw1T, db1, nullptr, nullptr, HIDb, 8192, 2048, 512, 1, 2048);
    gemm64(HIDb, dw2T, db2, T2, T3, nullptr, 8192, 512, 2048, 0, 512);
    final_k<<<(8192 * 64) / 256, 256, 0, stream>>>(T3, ow, ob, OUT, 8192);
}

// Round 7
// 1426.070 us; speedup vs baseline: 1.1252x; 1.0521x over previous
//
#include <hip/hip_runtime.h>
#include <cstdint>
#include <cmath>

// ---------------------------------------------------------------------------
// Informer forward. Round 22: breadth pass on the never-in-top-5 pool.
//  - topk_k: wave-per-(b,h) register argmax (was 315 barriers/block).
//  - ln_k: shfl reductions, 2 barriers (was 16).
//  - bnpart/bnfin: grid 256 (was 128 = half the CUs idle).
//  - elu_pool: 8 elems/thread vectorized.
//  - wprep_k: 8 weight transposes + w2t + bcat fused into ONE dispatch.
//  - GEMMs (gemm128 R19 / gemm12864 R20 / gemm64 R21) UNTOUCHED — they are
//    the measurement anchor; their top-5 rows should stay ~55us.
// jax.random via threefry2x32 (H2, verified R1).
// ---------------------------------------------------------------------------

#define HD __host__ __device__

typedef short short8 __attribute__((ext_vector_type(8)));
typedef float float4v __attribute__((ext_vector_type(4)));

typedef __attribute__((address_space(1))) const void gvoid;
typedef __attribute__((address_space(3))) void lvoid;

__device__ __forceinline__ void gl_lds16(const void* g, void* l) {
    // async global->LDS DMA, 16B/lane; LDS dest = wave-uniform base + lane*16
    __builtin_amdgcn_global_load_lds((gvoid*)g, (lvoid*)l, 16, 0, 0);
}

__device__ inline short f2bf(float f) {  // RNE
    unsigned u = __float_as_uint(f);
    unsigned r = u + 0x7FFFu + ((u >> 16) & 1u);
    return (short)(r >> 16);
}

HD inline unsigned rotl32(unsigned x, int r) { return (x << r) | (x >> (32 - r)); }
HD inline void tfround(unsigned& x0, unsigned& x1, int r) {
    x0 += x1; x1 = rotl32(x1, r); x1 ^= x0;
}
HD inline void threefry2x32(unsigned k0, unsigned k1, unsigned c0, unsigned c1,
                            unsigned& o0, unsigned& o1) {
    unsigned ks2 = k0 ^ k1 ^ 0x1BD11BDAu;
    unsigned x0 = c0 + k0, x1 = c1 + k1;
    tfround(x0, x1, 13); tfround(x0, x1, 15); tfround(x0, x1, 26); tfround(x0, x1, 6);
    x0 += k1; x1 += ks2 + 1u;
    tfround(x0, x1, 17); tfround(x0, x1, 29); tfround(x0, x1, 16); tfround(x0, x1, 24);
    x0 += ks2; x1 += k0 + 2u;
    tfround(x0, x1, 13); tfround(x0, x1, 15); tfround(x0, x1, 26); tfround(x0, x1, 6);
    x0 += k0; x1 += k1 + 3u;
    tfround(x0, x1, 17); tfround(x0, x1, 29); tfround(x0, x1, 16); tfround(x0, x1, 24);
    x0 += k1; x1 += ks2 + 4u;
    tfround(x0, x1, 13); tfround(x0, x1, 15); tfround(x0, x1, 26); tfround(x0, x1, 6);
    x0 += ks2; x1 += k0 + 5u;
    o0 = x0; o1 = x1;
}

// ---------------------------------------------------------------------------
// Kernels
// ---------------------------------------------------------------------------

// out = in + PE; outb = bf16(out). 8 elems/thread, sincosf per (sin,cos) pair.
__global__ void pe_add_k(const float* __restrict__ in, float* __restrict__ out,
                         short* __restrict__ outb, int total8) {
    int t = blockIdx.x * 256 + threadIdx.x;
    if (t >= total8) return;
    int e = t * 8;
    int d0 = e & 511;
    int l = (e >> 9) & 511;
    float4 v0 = *(const float4*)(in + e);
    float4 v1 = *(const float4*)(in + e + 4);
    float vin[8] = {v0.x, v0.y, v0.z, v0.w, v1.x, v1.y, v1.z, v1.w};
    float r[8];
    #pragma unroll
    for (int p = 0; p < 4; p++) {
        int d = d0 + 2 * p;
        float div = expf((float)d * (-0.017988946039016f));  // -ln(10000)/512
        float ang = (float)l * div;
        float s, c;
        sincosf(ang, &s, &c);
        r[2 * p] = vin[2 * p] + s;
        r[2 * p + 1] = vin[2 * p + 1] + c;
    }
    *(float4*)(out + e) = (float4){r[0], r[1], r[2], r[3]};
    *(float4*)(out + e + 4) = (float4){r[4], r[5], r[6], r[7]};
    short8 ob;
    #pragma unroll
    for (int p = 0; p < 8; p++) ob[p] = f2bf(r[p]);
    *(short8*)(outb + e) = ob;
}

// Fused weight prep: 8 fp32->bf16 transposes + dist_w repack + bias concat.
// blocks [0,5120): 32x32 transpose tiles; [5120,8192): w2t; [8192,8198): bcat.
__global__ __launch_bounds__(256) void wprep_k(
    const float* __restrict__ Wq, const float* __restrict__ Wk,
    const float* __restrict__ Wv, const float* __restrict__ Wo,
    const float* __restrict__ ew1, const float* __restrict__ ew2,
    const float* __restrict__ dw1, const float* __restrict__ dw2,
    short* __restrict__ WqkvT, short* __restrict__ WoT,
    short* __restrict__ e1T, short* __restrict__ e2T,
    short* __restrict__ d1T, short* __restrict__ d2T,
    const float* __restrict__ DW, short* __restrict__ W2T,
    const float* __restrict__ b0, const float* __restrict__ b1,
    const float* __restrict__ b2, float* __restrict__ bqkv) {
    int b = blockIdx.x;
    if (b < 5120) {
        const float* in; short* out; int K, N, tb;
        if (b < 1024) {
            int w = b >> 8; tb = b & 255;
            in = (w == 0) ? Wq : (w == 1) ? Wk : (w == 2) ? Wv : Wo;
            out = (w < 3) ? WqkvT + w * 512 * 512 : WoT;
            K = 512; N = 512;
        } else if (b < 2048) { in = ew1; out = e1T; K = 512; N = 2048; tb = b - 1024; }
        else if (b < 3072)   { in = ew2; out = e2T; K = 2048; N = 512; tb = b - 2048; }
        else if (b < 4096)   { in = dw1; out = d1T; K = 512; N = 2048; tb = b - 3072; }
        else                 { in = dw2; out = d2T; K = 2048; N = 512; tb = b - 4096; }
        int nbx = N >> 5;
        int k0 = (tb / nbx) << 5, n0 = (tb % nbx) << 5;
        __shared__ float tile[32][33];
        int c = threadIdx.x & 31, r0 = threadIdx.x >> 5;
        for (int rr = r0; rr < 32; rr += 8)
            tile[rr][c] = in[(size_t)(k0 + rr) * N + n0 + c];
        __syncthreads();
        for (int rr = r0; rr < 32; rr += 8)
            out[(size_t)(n0 + rr) * K + k0 + c] = f2bf(tile[c][rr]);
        return;
    }
    if (b < 8192) {  // dist_w (O,I,H) -> W2T[o][h*512+i], 786432 elems
        int t = (b - 5120) * 256 + threadIdx.x;
        int kk = t % 1536;
        int o = t / 1536;
        int h = kk / 512, i = kk % 512;
        W2T[t] = f2bf(DW[(size_t)o * 1536 + i * 3 + h]);
        return;
    }
    int t = (b - 8192) * 256 + threadIdx.x;  // bias concat, 1536 elems
    if (t < 1536)
        bqkv[t] = (t < 512) ? b0[t] : (t < 1024 ? b1[t - 512] : b2[t - 1024]);
}

__device__ inline void swizzle_bid(int bid, int nbx, int nby, int& bm, int& bn) {
    if ((nby & 7) == 0) {
        int stripe = nby >> 3;
        int x = bid & 7, w = bid >> 3;
        bn = w % nbx;
        bm = x * stripe + w / nbx;
    } else {
        bn = bid % nbx;
        bm = bid / nbx;
    }
}

// bf16 MFMA GEMM, 128x128 tile, BK=32; A bf16 [M][K], Bt bf16 [N][K].
// 3-buffer depth-2 counted pipeline + bank-deswizzled staging/reads. (R19)
__global__ __launch_bounds__(256) void gemm128_k(
    const short* __restrict__ A, const short* __restrict__ Bt,
    const float* __restrict__ bias, const float* __restrict__ res,
    float* __restrict__ C32, short* __restrict__ C16,
    int M, int N, int K, int relu, int ldC) {
    __shared__ short As[3][128 * 32];
    __shared__ short Bs[3][128 * 32];
    int tid = threadIdx.x;
    int wave = tid >> 6, lane = tid & 63;
    int wy = wave >> 1, wx = wave & 1;
    int rl = lane & 15, quad = lane >> 4;
    int bm, bn;
    swizzle_bid(blockIdx.x, N >> 7, M >> 7, bm, bn);
    bm <<= 7; bn <<= 7;

    int srow = (wave << 5) + (lane >> 2);
    int skol = (((lane & 3) ^ ((srow >> 1) & 3)) << 3);
    const short* ga0 = A + (size_t)(bm + srow) * K + skol;
    const short* ga1 = ga0 + (size_t)16 * K;
    const short* gb0 = Bt + (size_t)(bn + srow) * K + skol;
    const short* gb1 = gb0 + (size_t)16 * K;
    int lao = wave << 10;
    int ksw = (quad ^ ((rl >> 1) & 3)) << 3;  // read-side swizzle (same involution)

    float4v acc[4][4];
    #pragma unroll
    for (int i = 0; i < 4; i++)
        #pragma unroll
        for (int j = 0; j < 4; j++) acc[i][j] = (float4v){0.f, 0.f, 0.f, 0.f};

    int nsteps = K >> 5;
    auto stage = [&](int t, int bf) {
        int k0 = t << 5;
        gl_lds16(ga0 + k0, &As[bf][lao]);
        gl_lds16(ga1 + k0, &As[bf][lao + 512]);
        gl_lds16(gb0 + k0, &Bs[bf][lao]);
        gl_lds16(gb1 + k0, &Bs[bf][lao + 512]);
    };
    stage(0, 0);
    stage(1, 1);
    asm volatile("s_waitcnt vmcnt(4)" ::: "memory");
    __builtin_amdgcn_s_barrier();
    __builtin_amdgcn_sched_barrier(0);
    int cur = 0;
    for (int t = 0; t < nsteps; ++t) {
        if (t + 2 < nsteps) {
            int sb = cur + 2; if (sb >= 3) sb -= 3;
            stage(t + 2, sb);
        }
        short8 a[4], b[4];
        #pragma unroll
        for (int i = 0; i < 4; i++)
            a[i] = *(const short8*)&As[cur][(wy * 64 + i * 16 + rl) * 32 + ksw];
        #pragma unroll
        for (int j = 0; j < 4; j++)
            b[j] = *(const short8*)&Bs[cur][(wx * 64 + j * 16 + rl) * 32 + ksw];
        #pragma unroll
        for (int i = 0; i < 4; i++)
            #pragma unroll
            for (int j = 0; j < 4; j++)
                acc[i][j] = __builtin_amdgcn_mfma_f32_16x16x32_bf16(a[i], b[j], acc[i][j], 0, 0, 0);
        if (t + 2 < nsteps) {
            asm volatile("s_waitcnt vmcnt(4)" ::: "memory");
        } else {
            asm volatile("s_waitcnt vmcnt(0)" ::: "memory");
        }
        __builtin_amdgcn_s_barrier();
        __builtin_amdgcn_sched_barrier(0);
        cur = (cur == 2) ? 0 : cur + 1;
    }
    #pragma unroll
    for (int i = 0; i < 4; i++) {
        #pragma unroll
        for (int r = 0; r < 4; r++) {
            int gm = bm + wy * 64 + i * 16 + quad * 4 + r;
            #pragma unroll
            for (int j = 0; j < 4; j++) {
                int gn = bn + wx * 64 + j * 16 + rl;
                float v = acc[i][j][r];
                if (bias) v += bias[gn];
                if (relu) v = fmaxf(v, 0.f);
                if (res) v += res[(size_t)gm * ldC + gn];
                if (C32) C32[(size_t)gm * ldC + gn] = v;
                if (C16) C16[(size_t)gm * ldC + gn] = f2bf(v);
            }
        }
    }
}

// Dynamic LDS for the paired-pipeline GEMM (6 tile-buffers x 12KB = 72KB).
extern __shared__ short gls[];

// 128x64 tile, 4 waves 2x2, per-wave 64x32 output. Paired K-steps:
// 2 BK=32 tiles per barrier interval; 6 buffers, depth-2-pairs counted vmcnt.
__global__ __launch_bounds__(256) void gemm12864_k(
    const short* __restrict__ A, const short* __restrict__ Bt,
    const float* __restrict__ bias, const float* __restrict__ res,
    float* __restrict__ C32, short* __restrict__ C16,
    int M, int N, int K, int relu, int ldC) {
    int tid = threadIdx.x;
    int wave = tid >> 6, lane = tid & 63;
    int wy = wave >> 1, wx = wave & 1;
    int rl = lane & 15, quad = lane >> 4;
    int bm, bn;
    swizzle_bid(blockIdx.x, N >> 6, M >> 7, bm, bn);
    bm <<= 7; bn <<= 6;

    int arow = (wave << 5) + (lane >> 2);   // A: wave covers 32 rows (2 chunks)
    int brow = (wave << 4) + (lane >> 2);   // B: wave covers 16 rows (1 chunk)
    int ska = (((lane & 3) ^ ((arow >> 1) & 3)) << 3);
    int skb = (((lane & 3) ^ ((brow >> 1) & 3)) << 3);
    const short* ga0 = A + (size_t)(bm + arow) * K + ska;
    const short* ga1 = ga0 + (size_t)16 * K;
    const short* gb0 = Bt + (size_t)(bn + brow) * K + skb;
    int lao = wave << 10;   // A per-wave offset within a tile-buffer (shorts)
    int lbo = wave << 9;    // B per-wave offset
    int ksw = (quad ^ ((rl >> 1) & 3)) << 3;

    float4v acc[4][2];
    #pragma unroll
    for (int i = 0; i < 4; i++)
        #pragma unroll
        for (int j = 0; j < 2; j++) acc[i][j] = (float4v){0.f, 0.f, 0.f, 0.f};

    int nt = K >> 5;        // BK=32 tiles (even: K % 64 == 0 guaranteed by host)
    int niter = nt >> 1;    // paired iterations

    // tile-buffer bf in [0,6): A at gls + bf*6144, B at +4096 (shorts)
    auto stageT = [&](int t, int bf) {
        int k0 = t << 5;
        short* Ab = gls + bf * 6144;
        short* Bb = Ab + 4096;
        gl_lds16(ga0 + k0, Ab + lao);
        gl_lds16(ga1 + k0, Ab + lao + 512);
        gl_lds16(gb0 + k0, Bb + lbo);
    };
    auto computeT = [&](int bf) {
        const short* Ab = gls + bf * 6144;
        const short* Bb = Ab + 4096;
        short8 a[4], b[2];
        #pragma unroll
        for (int i = 0; i < 4; i++)
            a[i] = *(const short8*)&Ab[(wy * 64 + i * 16 + rl) * 32 + ksw];
        #pragma unroll
        for (int j = 0; j < 2; j++)
            b[j] = *(const short8*)&Bb[(wx * 32 + j * 16 + rl) * 32 + ksw];
        #pragma unroll
        for (int i = 0; i < 4; i++)
            #pragma unroll
            for (int j = 0; j < 2; j++)
                acc[i][j] = __builtin_amdgcn_mfma_f32_16x16x32_bf16(a[i], b[j], acc[i][j], 0, 0, 0);
    };

    // prologue: pairs 0,1 staged (12 loads); wait pair 0 (6 left in flight)
    stageT(0, 0); stageT(1, 1);
    stageT(2, 2); stageT(3, 3);
    asm volatile("s_waitcnt vmcnt(6)" ::: "memory");
    __builtin_amdgcn_s_barrier();
    __builtin_amdgcn_sched_barrier(0);
    int q = 0;  // pair-slot = p % 3; pair p lives in buffers {2q, 2q+1}
    for (int p = 0; p < niter; ++p) {
        if (p + 2 < niter) {
            int s = q + 2; if (s >= 3) s -= 3;
            int t0 = (p + 2) << 1;
            stageT(t0, 2 * s);
            stageT(t0 + 1, 2 * s + 1);
        }
        computeT(2 * q);
        computeT(2 * q + 1);
        // pair p+1 must be complete; pair p+2 stays in flight
        if (p + 2 < niter) {
            asm volatile("s_waitcnt vmcnt(6)" ::: "memory");
        } else {
            asm volatile("s_waitcnt vmcnt(0)" ::: "memory");
        }
        __builtin_amdgcn_s_barrier();
        __builtin_amdgcn_sched_barrier(0);
        q = (q == 2) ? 0 : q + 1;
    }
    #pragma unroll
    for (int i = 0; i < 4; i++) {
        #pragma unroll
        for (int r = 0; r < 4; r++) {
            int gm = bm + wy * 64 + i * 16 + quad * 4 + r;
            #pragma unroll
            for (int j = 0; j < 2; j++) {
                int gn = bn + wx * 32 + j * 16 + rl;
                float v = acc[i][j][r];
                if (bias) v += bias[gn];
                if (relu) v = fmaxf(v, 0.f);
                if (res) v += res[(size_t)gm * ldC + gn];
                if (C32) C32[(size_t)gm * ldC + gn] = v;
                if (C16) C16[(size_t)gm * ldC + gn] = f2bf(v);
            }
        }
    }
}

// 64x64-tile variant, BK=32. 4 waves, each 16x64.
// 2-phase DMA pipeline (R18) + XOR deswizzle (R19).
__global__ __launch_bounds__(256) void gemm64_k(
    const short* __restrict__ A, const short* __restrict__ Bt,
    const float* __restrict__ bias, const float* __restrict__ res,
    float* __restrict__ C32, short* __restrict__ C16,
    int M, int N, int K, int relu, int ldC) {
    __shared__ short As[2][64 * 32];
    __shared__ short Bs[2][64 * 32];
    int tid = threadIdx.x;
    int wave = tid >> 6, lane = tid & 63;
    int rl = lane & 15, quad = lane >> 4;
    int bm, bn;
    swizzle_bid(blockIdx.x, N >> 6, M >> 6, bm, bn);
    bm <<= 6; bn <<= 6;

    int srow = (wave << 4) + (lane >> 2);
    int skol = (((lane & 3) ^ ((srow >> 1) & 3)) << 3);
    const short* ga = A + (size_t)(bm + srow) * K + skol;
    const short* gb = Bt + (size_t)(bn + srow) * K + skol;
    int lof = wave << 9;  // 16 rows x 32 shorts
    int ksw = (quad ^ ((rl >> 1) & 3)) << 3;

    float4v acc[4];
    #pragma unroll
    for (int j = 0; j < 4; j++) acc[j] = (float4v){0.f, 0.f, 0.f, 0.f};

    int nsteps = K >> 5;
    auto stage = [&](int t, int bf) {
        int k0 = t << 5;
        gl_lds16(ga + k0, &As[bf][lof]);
        gl_lds16(gb + k0, &Bs[bf][lof]);
    };
    stage(0, 0);
    asm volatile("s_waitcnt vmcnt(0)" ::: "memory");
    __builtin_amdgcn_s_barrier();
    __builtin_amdgcn_sched_barrier(0);
    int cur = 0;
    for (int t = 0; t < nsteps; ++t) {
        if (t + 1 < nsteps) stage(t + 1, cur ^ 1);
        short8 a = *(const short8*)&As[cur][(wave * 16 + rl) * 32 + ksw];
        short8 b[4];
        #pragma unroll
        for (int j = 0; j < 4; j++)
            b[j] = *(const short8*)&Bs[cur][(j * 16 + rl) * 32 + ksw];
        #pragma unroll
        for (int j = 0; j < 4; j++)
            acc[j] = __builtin_amdgcn_mfma_f32_16x16x32_bf16(a, b[j], acc[j], 0, 0, 0);
        asm volatile("s_waitcnt vmcnt(0)" ::: "memory");
        __builtin_amdgcn_s_barrier();
        __builtin_amdgcn_sched_barrier(0);
        cur ^= 1;
    }
    #pragma unroll
    for (int r = 0; r < 4; r++) {
        int gm = bm + wave * 16 + quad * 4 + r;
        #pragma unroll
        for (int j = 0; j < 4; j++) {
            int gn = bn + j * 16 + rl;
            float v = acc[j][r];
            if (bias) v += bias[gn];
            if (relu) v = fmaxf(v, 0.f);
            if (res) v += res[(size_t)gm * ldC + gn];
            if (C32) C32[(size_t)gm * ldC + gn] = v;
            if (C16) C16[(size_t)gm * ldC + gn] = f2bf(v);
        }
    }
}

// idx[j] = threefry(rkey, (j, j+size)).second & mask   (H2, verified R1)
__global__ void ridx_k(unsigned k0, unsigned k1, int size, unsigned mask, int* __restrict__ idx) {
    int j = blockIdx.x * 256 + threadIdx.x;
    if (j >= size) return;
    unsigned o0, o1;
    threefry2x32(k0, k1, (unsigned)j, (unsigned)(j + size), o0, o1);
    idx[j] = (int)(o1 & mask);
}

// msamp, K-slab in LDS. One block per (b, h, l-half); grid 16*8*2 = 256.
extern __shared__ float kslab[];
__global__ __launch_bounds__(256) void msamp_lds_k(
    const float* __restrict__ Qp, const float* __restrict__ Kp,
    const int* __restrict__ idx, float* __restrict__ Mout,
    int LQ, int LK, int U, int ld) {
    int bid = blockIdx.x;
    int half = bid & 1;
    int bh = bid >> 1;
    int h = bh & 7, b = bh >> 3;
    const float* kbase = Kp + (size_t)b * LK * ld + h * 64;
    for (int t = threadIdx.x; t < LK * 16; t += 256) {
        int r = t >> 4, seg = t & 15;
        float4 v = *(const float4*)(kbase + (size_t)r * ld + seg * 4);
        float* dst = &kslab[r * 65 + seg * 4];
        dst[0] = v.x; dst[1] = v.y; dst[2] = v.z; dst[3] = v.w;
    }
    __syncthreads();
    int halfL = LQ >> 1;
    for (int li = threadIdx.x; li < halfL; li += 256) {
        int l = half * halfL + li;
        const float4* q = (const float4*)(Qp + (size_t)(b * LQ + l) * ld + h * 64);
        float qr[64];
        #pragma unroll
        for (int d4 = 0; d4 < 16; d4++) {
            float4 v = q[d4];
            qr[4 * d4] = v.x; qr[4 * d4 + 1] = v.y; qr[4 * d4 + 2] = v.z; qr[4 * d4 + 3] = v.w;
        }
        const int* ip = idx + l * U;
        float mx = -INFINITY, sm = 0.f;
        for (int s = 0; s < U; s++) {
            const float* kr = &kslab[ip[s] * 65];
            float acc = 0.f;
            #pragma unroll
            for (int d = 0; d < 64; d++) acc += qr[d] * kr[d];
            mx = fmaxf(mx, acc);
            sm += acc;
        }
        Mout[(size_t)bh * LQ + l] = mx - sm / (float)LK;
    }
}

// Fallback msamp if large dynamic-LDS attribute fails.
__global__ void msamp_k(const float* __restrict__ Qp, const float* __restrict__ Kp,
                        const int* __restrict__ idx, float* __restrict__ Mout,
                        int LQ, int LK, int U, int ld) {
    int t = blockIdx.x * 256 + threadIdx.x;
    int total = 16 * 8 * LQ * 4;
    if (t >= total) return;
    int p = t & 3;
    int rest = t >> 2;
    int l = rest % LQ;
    int h = (rest / LQ) & 7;
    int b = rest / (LQ * 8);
    const float4* q = (const float4*)(Qp + ((size_t)(b * LQ + l) * ld + h * 64));
    const float* kb = Kp + ((size_t)b * LK * ld + h * 64);
    float4 qr[16];
    #pragma unroll
    for (int d = 0; d < 16; d++) qr[d] = q[d];
    float mx = -INFINITY, sm = 0.f;
    for (int s = p; s < U; s += 4) {
        const float4* kr = (const float4*)(kb + (size_t)idx[l * U + s] * ld);
        float acc = 0.f;
        #pragma unroll
        for (int d = 0; d < 16; d++) {
            float4 kv = kr[d];
            acc += qr[d].x * kv.x + qr[d].y * kv.y + qr[d].z * kv.z + qr[d].w * kv.w;
        }
        mx = fmaxf(mx, acc);
        sm += acc;
    }
    mx = fmaxf(mx, __shfl_xor(mx, 1));
    mx = fmaxf(mx, __shfl_xor(mx, 2));
    sm += __shfl_xor(sm, 1);
    sm += __shfl_xor(sm, 2);
    if (p == 0)
        Mout[(size_t)((b * 8) + h) * LQ + l] = mx - sm / (float)LK;
}

// Wave-per-(b,h) register-resident iterative top-u; 4 waves/block, no LDS,
// no barriers (was 315 barriers/block). Lowest-index tie-break preserved.
__global__ __launch_bounds__(256) void topk_k(const float* __restrict__ M,
                                              int* __restrict__ top, int LQ, int u) {
    int wave = threadIdx.x >> 6, lane = threadIdx.x & 63;
    int bh = blockIdx.x * 4 + wave;
    const float* m = M + (size_t)bh * LQ;
    float v[8];
    int id[8];
    #pragma unroll
    for (int s = 0; s < 8; s++) {
        int l = s * 64 + lane;
        if (l < LQ) { v[s] = m[l]; id[s] = l; }
        else        { v[s] = -INFINITY; id[s] = 0x7FFFFFFF; }
    }
    int* o = top + bh * u;
    for (int j = 0; j < u; j++) {
        float bv = v[0]; int bi = id[0];
        #pragma unroll
        for (int s = 1; s < 8; s++)
            if (v[s] > bv || (v[s] == bv && id[s] < bi)) { bv = v[s]; bi = id[s]; }
        #pragma unroll
        for (int off = 32; off > 0; off >>= 1) {
            float v2 = __shfl_xor(bv, off);
            int i2 = __shfl_xor(bi, off);
            if (v2 > bv || (v2 == bv && i2 < bi)) { bv = v2; bi = i2; }
        }
        if (lane == 0) o[j] = bi;
        int ws = bi >> 6, wl = bi & 63;
        #pragma unroll
        for (int s = 0; s < 8; s++)          // compile-time index (rule #20)
            if (s == ws && lane == wl) v[s] = -INFINITY;
    }
}

// vm[b,c] = mean over l of V[b,l,c]; parallel over l. grid (16 c-chunks, 16 b).
__global__ __launch_bounds__(256) void vmean_k(const float* __restrict__ Vp,
                                               float* __restrict__ vm, int LK, int ld) {
    __shared__ float red[8][33];
    int b = blockIdx.y;
    int c0 = blockIdx.x * 32;
    int ci = threadIdx.x & 31, g = threadIdx.x >> 5;
    const float* base = Vp + (size_t)b * LK * ld + c0 + ci;
    float s = 0.f;
    for (int l = g; l < LK; l += 8) s += base[(size_t)l * ld];
    red[g][ci] = s;
    __syncthreads();
    if (threadIdx.x < 32) {
        float t = 0.f;
        #pragma unroll
        for (int g2 = 0; g2 < 8; g2++) t += red[g2][threadIdx.x];
        vm[b * 512 + c0 + threadIdx.x] = t / (float)LK;
    }
}

// ctxb[b,l,c] = bf16(vm[b,c]); 8 elems/thread.
__global__ void ctx_fill_k(const float* __restrict__ vm, short* __restrict__ ctxb,
                           int LQ, int total8) {
    int t = blockIdx.x * 256 + threadIdx.x;
    if (t >= total8) return;
    int e = t * 8;
    int c = e & 511;
    int b = e / (LQ << 9);
    float4 v0 = *(const float4*)(vm + b * 512 + c);
    float4 v1 = *(const float4*)(vm + b * 512 + c + 4);
    float vv[8] = {v0.x, v0.y, v0.z, v0.w, v1.x, v1.y, v1.z, v1.w};
    short8 ob;
    #pragma unroll
    for (int p = 0; p < 8; p++) ob[p] = f2bf(vv[p]);
    *(short8*)(ctxb + e) = ob;
}

// Flash-style ProbSparse attention: one block per (b, h, u-half), 256 threads.
__global__ __launch_bounds__(256) void attn_flash_k(
    const float* __restrict__ Qp, const float* __restrict__ Kp, const float* __restrict__ Vp,
    const int* __restrict__ top, short* __restrict__ ctxb, int LQ, int LK, int u, int ld) {
    __shared__ float qs[18][64];
    __shared__ int ls[18];
    __shared__ float kv[64][65];
    __shared__ float sc[18][512];
    int bid = blockIdx.x;
    int chunk = bid & 1;  // 2 chunks per (b,h)
    int h = (bid >> 1) & 7;
    int b = bid >> 4;
    int CH = (u + 1) >> 1;
    int r0 = chunk * CH;
    int nr = min(CH, u - r0);
    int tid = threadIdx.x;
    int wave = tid >> 6, lane = tid & 63;

    if (tid < nr) ls[tid] = top[((b * 8) + h) * u + r0 + tid];
    __syncthreads();
    for (int t = tid; t < nr * 16; t += 256) {
        int r = t >> 4, seg = t & 15;
        float4 v = *(const float4*)(Qp + ((size_t)(b * LQ + ls[r])) * ld + h * 64 + seg * 4);
        float* dst = &qs[r][seg * 4];
        dst[0] = v.x; dst[1] = v.y; dst[2] = v.z; dst[3] = v.w;
    }

    int ntile = LK >> 6;
    const float* kbase = Kp + ((size_t)b * LK) * ld + h * 64;
    for (int T = 0; T < ntile; T++) {
        __syncthreads();
        #pragma unroll
        for (int it = 0; it < 4; it++) {
            int t = tid + it * 256;
            int kk = t >> 4, seg = t & 15;
            float4 v = *(const float4*)(kbase + (size_t)(T * 64 + kk) * ld + seg * 4);
            float* dst = &kv[kk][seg * 4];
            dst[0] = v.x; dst[1] = v.y; dst[2] = v.z; dst[3] = v.w;
        }
        __syncthreads();
        for (int p = tid; p < nr * 64; p += 256) {
            int r = p >> 6, kk = p & 63;
            float acc = 0.f;
            #pragma unroll
            for (int d = 0; d < 64; d++) acc += qs[r][d] * kv[kk][d];
            sc[r][T * 64 + kk] = acc * 0.125f;  // 1/sqrt(64)
        }
    }
    __syncthreads();
    for (int r = wave; r < nr; r += 4) {
        float mx = -INFINITY;
        for (int k = lane; k < LK; k += 64) mx = fmaxf(mx, sc[r][k]);
        #pragma unroll
        for (int o = 32; o > 0; o >>= 1) mx = fmaxf(mx, __shfl_xor(mx, o));
        float s = 0.f;
        for (int k = lane; k < LK; k += 64) {
            float e = expf(sc[r][k] - mx);
            sc[r][k] = e;
            s += e;
        }
        #pragma unroll
        for (int o = 32; o > 0; o >>= 1) s += __shfl_xor(s, o);
        float inv = 1.0f / s;
        for (int k = lane; k < LK; k += 64) sc[r][k] *= inv;
    }
    float acc[5];
    #pragma unroll
    for (int i = 0; i < 5; i++) acc[i] = 0.f;
    const float* vbase = Vp + ((size_t)b * LK) * ld + h * 64;
    for (int T = 0; T < ntile; T++) {
        __syncthreads();
        #pragma unroll
        for (int it = 0; it < 4; it++) {
            int t = tid + it * 256;
            int kk = t >> 4, seg = t & 15;
            float4 v = *(const float4*)(vbase + (size_t)(T * 64 + kk) * ld + seg * 4);
            float* dst = &kv[kk][seg * 4];
            dst[0] = v.x; dst[1] = v.y; dst[2] = v.z; dst[3] = v.w;
        }
        __syncthreads();
        int ri = 0;
        for (int r = wave; r < nr; r += 4, ri++) {
            float a = 0.f;
            #pragma unroll
            for (int kk = 0; kk < 64; kk++) a += sc[r][T * 64 + kk] * kv[kk][lane];
            acc[ri] += a;
        }
    }
    int ri = 0;
    for (int r = wave; r < nr; r += 4, ri++)
        ctxb[((size_t)(b * LQ + ls[r])) * 512 + h * 64 + lane] = f2bf(acc[ri]);
}

// per-row layer norm, D=512; shfl reductions, 2 barriers (was 16).
__global__ __launch_bounds__(256) void ln_k(const float* __restrict__ in,
                                            float* __restrict__ out, short* __restrict__ outb) {
    __shared__ float wred[8];
    int r = blockIdx.x;
    int tid = threadIdx.x;
    int wave = tid >> 6, lane = tid & 63;
    const float* x = in + (size_t)r * 512;
    float a = x[tid], b = x[tid + 256];
    float s = a + b;
    #pragma unroll
    for (int o = 32; o > 0; o >>= 1) s += __shfl_xor(s, o);
    if (lane == 0) wred[wave] = s;
    __syncthreads();
    float mu = (wred[0] + wred[1] + wred[2] + wred[3]) * (1.f / 512.f);
    float d1 = a - mu, d2 = b - mu;
    float q = d1 * d1 + d2 * d2;
    #pragma unroll
    for (int o = 32; o > 0; o >>= 1) q += __shfl_xor(q, o);
    if (lane == 0) wred[wave + 4] = q;
    __syncthreads();
    float inv = 1.0f / sqrtf((wred[4] + wred[5] + wred[6] + wred[7]) * (1.f / 512.f) + 1e-5f);
    float v1 = d1 * inv, v2 = d2 * inv;
    out[(size_t)r * 512 + tid] = v1;
    out[(size_t)r * 512 + tid + 256] = v2;
    if (outb) {
        outb[(size_t)r * 512 + tid] = f2bf(v1);
        outb[(size_t)r * 512 + tid + 256] = f2bf(v2);
    }
}

// circular-pad im2col -> bf16; 8 elems/thread.
__global__ void xcat_k(const float* __restrict__ x, short* __restrict__ xc, int L, int total8) {
    int t = blockIdx.x * 256 + threadIdx.x;
    if (t >= total8) return;
    int e = t * 8;
    int i = e & 511;
    int q = e >> 9;
    int h = q % 3;
    int bt = q / 3;
    int tt = bt % L;
    int b = bt / L;
    int src = (tt + h - 1 + L) % L;
    const float* s = x + (size_t)(b * L + src) * 512 + i;
    float4 v0 = *(const float4*)s;
    float4 v1 = *(const float4*)(s + 4);
    float vv[8] = {v0.x, v0.y, v0.z, v0.w, v1.x, v1.y, v1.z, v1.w};
    short8 ob;
    #pragma unroll
    for (int p = 0; p < 8; p++) ob[p] = f2bf(vv[p]);
    *(short8*)(xc + e) = ob;
}

// bn stage 1: per-chunk per-channel sum/sumsq, coalesced row reads. grid=256.
__global__ __launch_bounds__(256) void bnpart_k(const float* __restrict__ y,
                                                float* __restrict__ ps, float* __restrict__ pq,
                                                int rows) {
    int chunk = blockIdx.x;
    int rpc = rows >> 8;
    int r0 = chunk * rpc;
    int tid = threadIdx.x;
    float s0 = 0.f, s1 = 0.f, q0 = 0.f, q1 = 0.f;
    for (int r = r0; r < r0 + rpc; r++) {
        float a = y[(size_t)r * 512 + tid];
        float b = y[(size_t)r * 512 + tid + 256];
        s0 += a; q0 += a * a;
        s1 += b; q1 += b * b;
    }
    ps[chunk * 512 + tid] = s0;
    ps[chunk * 512 + tid + 256] = s1;
    pq[chunk * 512 + tid] = q0;
    pq[chunk * 512 + tid + 256] = q1;
}

// bn stage 2: mu = s/n; var = q/n - mu^2.
__global__ void bnfin_k(const float* __restrict__ ps, const float* __restrict__ pq,
                        float* __restrict__ mu, float* __restrict__ var, int rows) {
    int o = blockIdx.x * 256 + threadIdx.x;
    if (o >= 512) return;
    float s = 0.f, q = 0.f;
    for (int c = 0; c < 256; c++) {
        s += ps[c * 512 + o];
        q += pq[c * 512 + o];
    }
    float m = s / (float)rows;
    mu[o] = m;
    var[o] = q / (float)rows - m * m;
}

// normalize -> max-pool(3,2,pad1) -> elu; 8 elems/thread.
__global__ void elu_pool_k(const float* __restrict__ y, const float* __restrict__ mu,
                           const float* __restrict__ var, float* __restrict__ out,
                           short* __restrict__ outb, int L, int total8) {
    int t = blockIdx.x * 256 + threadIdx.x;
    if (t >= total8) return;
    int e = t * 8;
    int o = e & 511;
    int tp = (e >> 9) % (L / 2);
    int b = (e >> 9) / (L / 2);
    float4 m0 = *(const float4*)(mu + o);
    float4 m1 = *(const float4*)(mu + o + 4);
    float4 g0 = *(const float4*)(var + o);
    float4 g1 = *(const float4*)(var + o + 4);
    float mm[8] = {m0.x, m0.y, m0.z, m0.w, m1.x, m1.y, m1.z, m1.w};
    float gg[8] = {g0.x, g0.y, g0.z, g0.w, g1.x, g1.y, g1.z, g1.w};
    float best[8];
    #pragma unroll
    for (int p = 0; p < 8; p++) best[p] = -INFINITY;
    #pragma unroll
    for (int dt = 0; dt < 3; dt++) {
        int tt = 2 * tp - 1 + dt;
        if (tt < 0 || tt >= L) continue;
        const float* row = y + (size_t)(b * L + tt) * 512 + o;
        float4 r0 = *(const float4*)row;
        float4 r1 = *(const float4*)(row + 4);
        float rr[8] = {r0.x, r0.y, r0.z, r0.w, r1.x, r1.y, r1.z, r1.w};
        #pragma unroll
        for (int p = 0; p < 8; p++) best[p] = fmaxf(best[p], rr[p]);
    }
    float res[8];
    short8 ob;
    #pragma unroll
    for (int p = 0; p < 8; p++) {
        float m = (best[p] - mm[p]) / sqrtf(gg[p] + 1e-5f);
        float r = m > 0.f ? m : expm1f(m);
        res[p] = r;
        ob[p] = f2bf(r);
    }
    *(float4*)(out + e) = (float4){res[0], res[1], res[2], res[3]};
    *(float4*)(out + e + 4) = (float4){res[4], res[5], res[6], res[7]};
    *(short8*)(outb + e) = ob;
}

// out[r] = dot(x[r,:512], w) + b
__global__ void final_k(const float* __restrict__ x, const float* __restrict__ w,
                        const float* __restrict__ bb, float* __restrict__ out, int rows) {
    int gid = blockIdx.x * 256 + threadIdx.x;
    int wid = gid >> 6;
    int lane = gid & 63;
    if (wid >= rows) return;
    const float* xr = x + (size_t)wid * 512;
    float acc = 0.f;
    for (int k = lane; k < 512; k += 64) acc += xr[k] * w[k];
    for (int off = 32; off > 0; off >>= 1) acc += __shfl_down(acc, off);
    if (lane == 0) out[wid] = acc + bb[0];
}

// ---------------------------------------------------------------------------
// Host driver
// ---------------------------------------------------------------------------

static inline int iceil_log(int L) { return (int)ceil(log((double)L)); }
static inline int imin(int a, int b) { return a < b ? a : b; }

extern "C" void kernel_launch(void* const* d_in, const int* in_sizes, int n_in,
                              void* d_out, int out_size, void* d_ws, size_t ws_size,
                              hipStream_t stream) {
    const float* IN  = (const float*)d_in[0];
    const float* Wq  = (const float*)d_in[1];
    const float* bq  = (const float*)d_in[2];
    const float* Wk  = (const float*)d_in[3];
    const float* bk  = (const float*)d_in[4];
    const float* Wv  = (const float*)d_in[5];
    const float* bv  = (const float*)d_in[6];
    const float* Wo  = (const float*)d_in[7];
    const float* bo  = (const float*)d_in[8];
    const float* ew1 = (const float*)d_in[9];
    const float* eb1 = (const float*)d_in[10];
    const float* ew2 = (const float*)d_in[11];
    const float* eb2 = (const float*)d_in[12];
    const float* dw1 = (const float*)d_in[13];
    const float* db1 = (const float*)d_in[14];
    const float* dw2 = (const float*)d_in[15];
    const float* db2 = (const float*)d_in[16];
    const float* DW  = (const float*)d_in[17];
    const float* db  = (const float*)d_in[18];
    const float* ow  = (const float*)d_in[19];
    const float* ob  = (const float*)d_in[20];
    float* OUT = (float*)d_out;

    float* ws = (float*)d_ws;
    size_t off = 0;
    auto alloc = [&](size_t n) { float* p = ws + off; off += n; return p; };
    float* PE   = alloc(4194304);
    short* PEb  = (short*)alloc(2097152);
    float* QKV  = alloc(12582912);
    float* CTX  = alloc(4194304);
    short* CTXb = (short*)alloc(2097152);
    float* T1   = alloc(4194304);
    short* T1b  = (short*)alloc(2097152);
    float* XLN  = alloc(4194304);
    short* XLNb = (short*)alloc(2097152);
    float* T2   = alloc(4194304);
    short* T2b  = (short*)alloc(2097152);
    float* T3   = alloc(4194304);
    short* HIDb = (short*)alloc(8388608);
    float* D1   = alloc(2097152);
    short* D1b  = (short*)alloc(1048576);
    float* D2   = alloc(1048576);
    short* D2b  = (short*)alloc(524288);
    short* Ebb  = (short*)alloc(262144);
    float* Ebf  = alloc(524288);
    float* MB   = alloc(65536);
    float* VM   = alloc(8192);
    float* MU   = alloc(512);
    float* VARb = alloc(512);
    float* BQKV = alloc(1536);
    float* PS   = alloc(131072);
    float* PQ   = alloc(131072);
    int* IDX  = (int*)alloc(17920);
    int* TOPB = (int*)alloc(4480);
    short* WqkvT = (short*)alloc(393216);
    short* WoT   = (short*)alloc(131072);
    short* ew1T  = (short*)alloc(524288);
    short* ew2T  = (short*)alloc(524288);
    short* dw1T  = (short*)alloc(524288);
    short* dw2T  = (short*)alloc(524288);
    short* W2T   = (short*)alloc(393216);
    (void)ws_size; (void)n_in; (void)in_sizes; (void)out_size;

    static_assert(512 * 65 * 4 == 133120, "");
    hipError_t attr_ok = hipFuncSetAttribute(
        (const void*)msamp_lds_k, hipFuncAttributeMaxDynamicSharedMemorySize, 133120);
    // 72KB dynamic LDS for the paired-pipeline GEMM
    hipError_t attr_g = hipFuncSetAttribute(
        (const void*)gemm12864_k, hipFuncAttributeMaxDynamicSharedMemorySize, 73728);

    auto gemm128 = [&](const short* A, const short* Bt, const float* bias, const float* res,
                       float* C32, short* C16, int M, int N, int K, int relu, int ldC) {
        gemm128_k<<<(N / 128) * (M / 128), 256, 0, stream>>>(A, Bt, bias, res, C32, C16,
                                                             M, N, K, relu, ldC);
    };
    // N%64==0 GEMMs: paired-pipeline 128x64 tile for big M, else 64x64.
    auto gemm64 = [&](const short* A, const short* Bt, const float* bias, const float* res,
                      float* C32, short* C16, int M, int N, int K, int relu, int ldC) {
        if (attr_g == hipSuccess && M >= 8192 && (M & 127) == 0 && (N & 63) == 0 &&
            (K & 63) == 0) {
            gemm12864_k<<<(N / 64) * (M / 128), 256, 73728, stream>>>(A, Bt, bias, res,
                                                                      C32, C16, M, N, K,
                                                                      relu, ldC);
        } else {
            gemm64_k<<<(N / 64) * (M / 64), 256, 0, stream>>>(A, Bt, bias, res, C32, C16,
                                                              M, N, K, relu, ldC);
        }
    };

    auto attn = [&](const short* qinb, const short* kvinb, const float* resp,
                    float* out32, short* out16, int LQ, int LK, int ikey) {
        int Mq = 16 * LQ, Mk = 16 * LK;
        const int ld = 1536;
        float* Qp = QKV;
        float* Kp = QKV + 512;
        float* Vp = QKV + 1024;
        if (qinb == kvinb) {
            gemm128(qinb, WqkvT, BQKV, nullptr, QKV, nullptr, Mq, 1536, 512, 0, ld);
        } else {
            gemm64(qinb, WqkvT, BQKV, nullptr, QKV, nullptr, Mq, 512, 512, 0, ld);
            gemm64(kvinb, WqkvT + 512 * 512, BQKV + 512, nullptr, QKV + 512, nullptr,
                   Mk, 1024, 512, 0, ld);
        }
        int U = imin(5 * iceil_log(LK), LK);
        int u = imin(5 * iceil_log(LQ), LQ);
        unsigned rk0, rk1;
        threefry2x32(0u, 42u, 0u, (unsigned)ikey, rk0, rk1);
        int size = LQ * U;
        ridx_k<<<(size + 255) / 256, 256, 0, stream>>>(rk0, rk1, size, (unsigned)(LK - 1), IDX);
        size_t shbytes = (size_t)LK * 65 * 4;
        if (attr_ok == hipSuccess || shbytes <= 65536) {
            msamp_lds_k<<<16 * 8 * 2, 256, shbytes, stream>>>(Qp, Kp, IDX, MB, LQ, LK, U, ld);
        } else {
            int totM = 16 * 8 * LQ * 4;
            msamp_k<<<(totM + 255) / 256, 256, 0, stream>>>(Qp, Kp, IDX, MB, LQ, LK, U, ld);
        }
        topk_k<<<32, 256, 0, stream>>>(MB, TOPB, LQ, u);
        vmean_k<<<dim3(16, 16), 256, 0, stream>>>(Vp, VM, LK, ld);
        int totC8 = 16 * LQ * 512 / 8;
        ctx_fill_k<<<(totC8 + 255) / 256, 256, 0, stream>>>(VM, CTXb, LQ, totC8);
        attn_flash_k<<<16 * 8 * 2, 256, 0, stream>>>(Qp, Kp, Vp, TOPB, CTXb, LQ, LK, u, ld);
        gemm64(CTXb, WoT, bo, resp, out32, out16, Mq, 512, 512, 0, 512);
    };

    auto encoder = [&](const short* Xb, const float* X, int L, int ikey, float* OUTenc) {
        int M = 16 * L;
        attn(Xb, Xb, X, T1, nullptr, L, L, ikey);
        ln_k<<<M, 256, 0, stream>>>(T1, XLN, XLNb);
        gemm128(XLNb, ew1T, eb1, nullptr, nullptr, HIDb, M, 2048, 512, 1, 2048);
        gemm64(HIDb, ew2T, eb2, XLN, T2, nullptr, M, 512, 2048, 0, 512);
        ln_k<<<M, 256, 0, stream>>>(T2, OUTenc, nullptr);
    };

    auto distill = [&](const float* X, int L, float* OUTd, short* OUTdb) {
        int M = 16 * L;
        int tot8 = M * 1536 / 8;
        xcat_k<<<(tot8 + 255) / 256, 256, 0, stream>>>(X, HIDb, L, tot8);
        gemm64(HIDb, W2T, db, nullptr, CTX, nullptr, M, 512, 1536, 0, 512);
        bnpart_k<<<256, 256, 0, stream>>>(CTX, PS, PQ, M);
        bnfin_k<<<2, 256, 0, stream>>>(PS, PQ, MU, VARb, M);
        int toto8 = 16 * (L / 2) * 512 / 8;
        elu_pool_k<<<(toto8 + 255) / 256, 256, 0, stream>>>(CTX, MU, VARb, OUTd, OUTdb, L, toto8);
    };

    // --- weight conversion (once per launch, single fused dispatch) ---
    wprep_k<<<8198, 256, 0, stream>>>(Wq, Wk, Wv, Wo, ew1, ew2, dw1, dw2,
                                      WqkvT, WoT, ew1T, ew2T, dw1T, dw2T,
                                      DW, W2T, bq, bk, bv, BQKV);

    // --- forward ---
    int totPE8 = 16 * 512 * 512 / 8;
    pe_add_k<<<(totPE8 + 255) / 256, 256, 0, stream>>>(IN, PE, PEb, totPE8);

    encoder(PEb, PE, 512, 0, T3); distill(T3, 512, D1, D1b);
    encoder(D1b, D1, 256, 1, T3); distill(T3, 256, D2, D2b);
    encoder(D2b, D2, 128, 2, T3); distill(T3, 128, Ebf, Ebb);

    attn(PEb, PEb, PE, T1, T1b, 512, 512, 3);   // out1 = dec_inp + attn
    attn(T1b, Ebb, T1, T2, T2b, 512, 64, 4);    // out2 = out1 + cross-attn
    gemm128(T2b, dw1T, db1, nullptr, nullptr, HIDb, 8192, 2048, 512, 1, 2048);
    gemm64(HIDb, dw2T, db2, T2, T3, nullptr, 8192, 512, 2048, 0, 512);
    final_k<<<(8192 * 64) / 256, 256, 0, stream>>>(T3, ow, ob, OUT, 8192);
}